// Round 2
// baseline (11025.203 us; speedup 1.0000x reference)
//
#include <hip/hip_runtime.h>
#include <math.h>

#define USER_NUM 100000
#define ITEM_NUM 50000
#define FACTOR   64
#define LAMADA   0.0001f

// dst[r,f] = src[r,f] * d[r]   (float4-vectorized: 16 float4 per 64-wide row)
__global__ void init_scale(const float* __restrict__ src, const float* __restrict__ d,
                           float* __restrict__ dst, int n_rows) {
    int gid = blockIdx.x * blockDim.x + threadIdx.x;
    int total = n_rows * 16;
    if (gid >= total) return;
    int r = gid >> 4;
    float s = d[r];
    float4 v = ((const float4*)src)[gid];
    v.x *= s; v.y *= s; v.z *= s; v.w *= s;
    ((float4*)dst)[gid] = v;
}

// Fused both-direction SPMM edge pass:
//   dstU[u,:] += srcI[i,:] * ui_val     dstI[i,:] += srcU[u,:] * iu_val
// 16 threads per edge, one float4 per thread.
__global__ void edge_spmm(const float* __restrict__ srcU, const float* __restrict__ srcI,
                          float* __restrict__ dstU, float* __restrict__ dstI,
                          const int* __restrict__ u_idx, const int* __restrict__ i_idx,
                          const float* __restrict__ ui_vals, const float* __restrict__ iu_vals,
                          int n_edges) {
    long long gid = (long long)blockIdx.x * blockDim.x + threadIdx.x;
    int e = (int)(gid >> 4);
    if (e >= n_edges) return;
    int sub = ((int)gid & 15) * 4;
    int u = u_idx[e], i = i_idx[e];
    float uv = ui_vals[e], iv = iu_vals[e];
    size_t uo = (size_t)u * FACTOR + sub;
    size_t io = (size_t)i * FACTOR + sub;
    float4 a = *(const float4*)(srcI + io);   // item row -> user dst
    float4 b = *(const float4*)(srcU + uo);   // user row -> item dst
    float* du = dstU + uo;
    float* di = dstI + io;
    atomicAdd(du + 0, a.x * uv);
    atomicAdd(du + 1, a.y * uv);
    atomicAdd(du + 2, a.z * uv);
    atomicAdd(du + 3, a.w * uv);
    atomicAdd(di + 0, b.x * iv);
    atomicAdd(di + 1, b.y * iv);
    atomicAdd(di + 2, b.z * iv);
    atomicAdd(di + 3, b.w * iv);
}

// One wave (64 lanes) per batch sample: gather 3 rows, dot-products via shfl,
// accumulate the three reduction terms with 3 atomics per wave.
__global__ void batch_loss(const float* __restrict__ eu, const float* __restrict__ ei,
                           const float* __restrict__ g1u, const float* __restrict__ g1i,
                           const float* __restrict__ g2u, const float* __restrict__ g2i,
                           const int* __restrict__ user, const int* __restrict__ item_i,
                           const int* __restrict__ item_j, float* __restrict__ acc, int batch) {
    int gid = blockIdx.x * blockDim.x + threadIdx.x;
    int w = gid >> 6;
    int lane = threadIdx.x & 63;
    if (w >= batch) return;
    int uu = user[w], ii = item_i[w], jj = item_j[w];
    size_t uo = (size_t)uu * FACTOR + lane;
    size_t io = (size_t)ii * FACTOR + lane;
    size_t jo = (size_t)jj * FACTOR + lane;
    float uvv = eu[uo] + g1u[uo] + g2u[uo];
    float piv = ei[io] + g1i[io] + g2i[io];
    float pjv = ei[jo] + g1i[jo] + g2i[jo];
    float di  = uvv * piv;
    float dj  = uvv * pjv;
    float su2 = uvv * uvv;
    float sp2 = piv * piv + pjv * pjv;
    for (int off = 32; off; off >>= 1) {
        di  += __shfl_down(di,  off, 64);
        dj  += __shfl_down(dj,  off, 64);
        su2 += __shfl_down(su2, off, 64);
        sp2 += __shfl_down(sp2, off, 64);
    }
    if (lane == 0) {
        float x  = -(di - dj);
        float sp = fmaxf(x, 0.f) + log1pf(expf(-fabsf(x)));
        atomicAdd(acc + 0, su2);
        atomicAdd(acc + 1, sp2);
        atomicAdd(acc + 2, sp);
    }
}

__global__ void finalize(const float* __restrict__ acc, float* __restrict__ out, int batch) {
    if (threadIdx.x == 0 && blockIdx.x == 0) {
        float inv_b  = 1.0f / (float)batch;
        float inv_bf = 1.0f / (float)(batch * FACTOR);
        out[0] = acc[2] * inv_b + LAMADA * acc[0] * inv_bf + LAMADA * acc[1] * inv_bf;
    }
}

extern "C" void kernel_launch(void* const* d_in, const int* in_sizes, int n_in,
                              void* d_out, int out_size, void* d_ws, size_t ws_size,
                              hipStream_t stream) {
    const float* eu      = (const float*)d_in[0];
    const float* ei      = (const float*)d_in[1];
    const int*   u_idx   = (const int*)d_in[2];
    const int*   i_idx   = (const int*)d_in[3];
    const float* ui_vals = (const float*)d_in[4];
    const float* iu_vals = (const float*)d_in[5];
    const float* d_i     = (const float*)d_in[6];
    const float* d_j     = (const float*)d_in[7];
    const int*   user    = (const int*)d_in[8];
    const int*   item_i  = (const int*)d_in[9];
    const int*   item_j  = (const int*)d_in[10];
    int n_edges = in_sizes[2];
    int batch   = in_sizes[8];
    float* out  = (float*)d_out;

    float* ws  = (float*)d_ws;
    float* g1u = ws;
    float* g1i = g1u + (size_t)USER_NUM * FACTOR;
    float* g2u = g1i + (size_t)ITEM_NUM * FACTOR;
    float* g2i = g2u + (size_t)USER_NUM * FACTOR;
    float* acc = g2i + (size_t)ITEM_NUM * FACTOR;

    hipMemsetAsync(acc, 0, 4 * sizeof(float), stream);

    // Layer 1 init: g1u = eu*d_i, g1i = ei*d_j
    init_scale<<<(USER_NUM * 16 + 255) / 256, 256, 0, stream>>>(eu, d_i, g1u, USER_NUM);
    init_scale<<<(ITEM_NUM * 16 + 255) / 256, 256, 0, stream>>>(ei, d_j, g1i, ITEM_NUM);

    // Layer 1 edge pass (both directions fused)
    {
        long long tot = (long long)n_edges * 16;
        int blocks = (int)((tot + 255) / 256);
        edge_spmm<<<blocks, 256, 0, stream>>>(eu, ei, g1u, g1i,
                                              u_idx, i_idx, ui_vals, iu_vals, n_edges);
    }

    // Layer 2 init: g2u = g1u*d_i, g2i = g1i*d_j
    init_scale<<<(USER_NUM * 16 + 255) / 256, 256, 0, stream>>>(g1u, d_i, g2u, USER_NUM);
    init_scale<<<(ITEM_NUM * 16 + 255) / 256, 256, 0, stream>>>(g1i, d_j, g2i, ITEM_NUM);

    // Layer 2 edge pass
    {
        long long tot = (long long)n_edges * 16;
        int blocks = (int)((tot + 255) / 256);
        edge_spmm<<<blocks, 256, 0, stream>>>(g1u, g1i, g2u, g2i,
                                              u_idx, i_idx, ui_vals, iu_vals, n_edges);
    }

    // Final reduction
    batch_loss<<<(batch * 64 + 255) / 256, 256, 0, stream>>>(eu, ei, g1u, g1i, g2u, g2i,
                                                             user, item_i, item_j, acc, batch);
    finalize<<<1, 64, 0, stream>>>(acc, out, batch);
}

// Round 3
// 2271.852 us; speedup vs baseline: 4.8530x; 4.8530x over previous
//
#include <hip/hip_runtime.h>
#include <math.h>

#define USER_NUM 100000
#define ITEM_NUM 50000
#define FACTOR   64
#define LAMADA   0.0001f

// ---------------- CSR build ----------------

__global__ void histogram(const int* __restrict__ u_idx, const int* __restrict__ i_idx,
                          int* __restrict__ cnt_u, int* __restrict__ cnt_i, int n_edges) {
    int e = blockIdx.x * blockDim.x + threadIdx.x;
    if (e >= n_edges) return;
    atomicAdd(&cnt_u[u_idx[e]], 1);
    atomicAdd(&cnt_i[i_idx[e]], 1);
}

// Single-block exclusive scan over n counters (n up to ~100k). Writes ptr[0..n].
__global__ void exscan(const int* __restrict__ cnt, int* __restrict__ ptr, int n) {
    __shared__ int sdata[1024];
    __shared__ int carry_s;
    int tid = threadIdx.x;
    if (tid == 0) carry_s = 0;
    __syncthreads();
    for (int base = 0; base < n; base += 1024) {
        int idx = base + tid;
        int x = (idx < n) ? cnt[idx] : 0;
        sdata[tid] = x;
        __syncthreads();
        for (int off = 1; off < 1024; off <<= 1) {
            int t = (tid >= off) ? sdata[tid - off] : 0;
            __syncthreads();
            sdata[tid] += t;
            __syncthreads();
        }
        int inc = sdata[tid];       // inclusive scan of this chunk
        int carry = carry_s;
        if (idx < n) ptr[idx] = carry + inc - x;   // exclusive
        __syncthreads();
        if (tid == 1023) carry_s = carry + inc;    // inc of lane 1023 == chunk total
        __syncthreads();
    }
    if (tid == 0) ptr[n] = carry_s;
}

// Scatter edges into both sorted orders using cursor atomics.
__global__ void scatter(const int* __restrict__ u_idx, const int* __restrict__ i_idx,
                        const float* __restrict__ ui_vals, const float* __restrict__ iu_vals,
                        int* __restrict__ cur_u, int* __restrict__ cur_i,
                        int* __restrict__ iC, float* __restrict__ vC,
                        int* __restrict__ uC, float* __restrict__ wC, int n_edges) {
    int e = blockIdx.x * blockDim.x + threadIdx.x;
    if (e >= n_edges) return;
    int u = u_idx[e], i = i_idx[e];
    int pu = atomicAdd(&cur_u[u], 1);
    iC[pu] = i;
    vC[pu] = ui_vals[e];
    int pi = atomicAdd(&cur_i[i], 1);
    uC[pi] = u;
    wC[pi] = iu_vals[e];
}

// ---------------- gather SPMM ----------------
// out[r,:] = sum_{k in row r} val[k] * src[col[k],:]  +  self[r,:] * d[r]
// One 64-lane wave per row, lane = feature. No atomics.
__global__ void csr_spmm(const int* __restrict__ ptr, const int* __restrict__ col,
                         const float* __restrict__ val, const float* __restrict__ src,
                         const float* __restrict__ self, const float* __restrict__ d,
                         float* __restrict__ out, int n_rows) {
    int w = (blockIdx.x * blockDim.x + threadIdx.x) >> 6;
    int lane = threadIdx.x & 63;
    if (w >= n_rows) return;
    int start = ptr[w], end = ptr[w + 1];
    float acc = self[(size_t)w * FACTOR + lane] * d[w];
    for (int k = start; k < end; ++k) {
        int   c = col[k];
        float v = val[k];
        acc += src[(size_t)c * FACTOR + lane] * v;
    }
    out[(size_t)w * FACTOR + lane] = acc;
}

// ---------------- fallback (atomic) path kernels ----------------

__global__ void init_scale(const float* __restrict__ src, const float* __restrict__ d,
                           float* __restrict__ dst, int n_rows) {
    int gid = blockIdx.x * blockDim.x + threadIdx.x;
    int total = n_rows * 16;
    if (gid >= total) return;
    int r = gid >> 4;
    float s = d[r];
    float4 v = ((const float4*)src)[gid];
    v.x *= s; v.y *= s; v.z *= s; v.w *= s;
    ((float4*)dst)[gid] = v;
}

__global__ void edge_spmm(const float* __restrict__ srcU, const float* __restrict__ srcI,
                          float* __restrict__ dstU, float* __restrict__ dstI,
                          const int* __restrict__ u_idx, const int* __restrict__ i_idx,
                          const float* __restrict__ ui_vals, const float* __restrict__ iu_vals,
                          int n_edges) {
    long long gid = (long long)blockIdx.x * blockDim.x + threadIdx.x;
    int e = (int)(gid >> 4);
    if (e >= n_edges) return;
    int sub = ((int)gid & 15) * 4;
    int u = u_idx[e], i = i_idx[e];
    float uv = ui_vals[e], iv = iu_vals[e];
    size_t uo = (size_t)u * FACTOR + sub;
    size_t io = (size_t)i * FACTOR + sub;
    float4 a = *(const float4*)(srcI + io);
    float4 b = *(const float4*)(srcU + uo);
    float* du = dstU + uo;
    float* di = dstI + io;
    atomicAdd(du + 0, a.x * uv); atomicAdd(du + 1, a.y * uv);
    atomicAdd(du + 2, a.z * uv); atomicAdd(du + 3, a.w * uv);
    atomicAdd(di + 0, b.x * iv); atomicAdd(di + 1, b.y * iv);
    atomicAdd(di + 2, b.z * iv); atomicAdd(di + 3, b.w * iv);
}

// ---------------- loss ----------------

__global__ void batch_loss(const float* __restrict__ eu, const float* __restrict__ ei,
                           const float* __restrict__ g1u, const float* __restrict__ g1i,
                           const float* __restrict__ g2u, const float* __restrict__ g2i,
                           const int* __restrict__ user, const int* __restrict__ item_i,
                           const int* __restrict__ item_j, float* __restrict__ acc, int batch) {
    int gid = blockIdx.x * blockDim.x + threadIdx.x;
    int w = gid >> 6;
    int lane = threadIdx.x & 63;
    if (w >= batch) return;
    int uu = user[w], ii = item_i[w], jj = item_j[w];
    size_t uo = (size_t)uu * FACTOR + lane;
    size_t io = (size_t)ii * FACTOR + lane;
    size_t jo = (size_t)jj * FACTOR + lane;
    float uvv = eu[uo] + g1u[uo] + g2u[uo];
    float piv = ei[io] + g1i[io] + g2i[io];
    float pjv = ei[jo] + g1i[jo] + g2i[jo];
    float di  = uvv * piv;
    float dj  = uvv * pjv;
    float su2 = uvv * uvv;
    float sp2 = piv * piv + pjv * pjv;
    for (int off = 32; off; off >>= 1) {
        di  += __shfl_down(di,  off, 64);
        dj  += __shfl_down(dj,  off, 64);
        su2 += __shfl_down(su2, off, 64);
        sp2 += __shfl_down(sp2, off, 64);
    }
    if (lane == 0) {
        float x  = -(di - dj);
        float sp = fmaxf(x, 0.f) + log1pf(expf(-fabsf(x)));
        atomicAdd(acc + 0, su2);
        atomicAdd(acc + 1, sp2);
        atomicAdd(acc + 2, sp);
    }
}

__global__ void finalize(const float* __restrict__ acc, float* __restrict__ out, int batch) {
    if (threadIdx.x == 0 && blockIdx.x == 0) {
        float inv_b  = 1.0f / (float)batch;
        float inv_bf = 1.0f / (float)(batch * FACTOR);
        out[0] = acc[2] * inv_b + LAMADA * acc[0] * inv_bf + LAMADA * acc[1] * inv_bf;
    }
}

extern "C" void kernel_launch(void* const* d_in, const int* in_sizes, int n_in,
                              void* d_out, int out_size, void* d_ws, size_t ws_size,
                              hipStream_t stream) {
    const float* eu      = (const float*)d_in[0];
    const float* ei      = (const float*)d_in[1];
    const int*   u_idx   = (const int*)d_in[2];
    const int*   i_idx   = (const int*)d_in[3];
    const float* ui_vals = (const float*)d_in[4];
    const float* iu_vals = (const float*)d_in[5];
    const float* d_i     = (const float*)d_in[6];
    const float* d_j     = (const float*)d_in[7];
    const int*   user    = (const int*)d_in[8];
    const int*   item_i  = (const int*)d_in[9];
    const int*   item_j  = (const int*)d_in[10];
    int n_edges = in_sizes[2];
    int batch   = in_sizes[8];
    float* out  = (float*)d_out;

    const size_t FU = (size_t)USER_NUM * FACTOR;   // 6.4M
    const size_t FI = (size_t)ITEM_NUM * FACTOR;   // 3.2M
    const size_t NE = (size_t)n_edges;

    // Workspace layout (words)
    float* ws  = (float*)d_ws;
    float* g1u = ws;                         // FU
    float* g1i = g1u + FU;                   // FI
    float* g2u = g1i + FI;                   // FU
    float* g2i = g2u + FU;                   // FI
    int*   iC  = (int*)(g2i + FI);           // NE  (i col sorted by u)
    float* vC  = (float*)(iC + NE);          // NE
    int*   uC  = (int*)(vC + NE);            // NE  (u col sorted by i)
    float* wC  = (float*)(uC + NE);          // NE
    int*   ptr_u = (int*)(wC + NE);          // USER_NUM+1
    int*   ptr_i = ptr_u + (USER_NUM + 1);   // ITEM_NUM+1
    int*   cur_u = ptr_i + (ITEM_NUM + 1);   // USER_NUM
    int*   cur_i = cur_u + USER_NUM;         // ITEM_NUM
    float* acc   = (float*)(cur_i + ITEM_NUM); // 4

    size_t need_bytes = ((size_t)(acc + 4) - (size_t)d_ws);

    hipMemsetAsync(acc, 0, 4 * sizeof(float), stream);

    if (ws_size >= need_bytes) {
        // ---- CSR build ----
        hipMemsetAsync(cur_u, 0, (size_t)(USER_NUM + ITEM_NUM) * sizeof(int), stream);
        histogram<<<(n_edges + 255) / 256, 256, 0, stream>>>(u_idx, i_idx, cur_u, cur_i, n_edges);
        exscan<<<1, 1024, 0, stream>>>(cur_u, ptr_u, USER_NUM);
        exscan<<<1, 1024, 0, stream>>>(cur_i, ptr_i, ITEM_NUM);
        hipMemcpyAsync(cur_u, ptr_u, USER_NUM * sizeof(int), hipMemcpyDeviceToDevice, stream);
        hipMemcpyAsync(cur_i, ptr_i, ITEM_NUM * sizeof(int), hipMemcpyDeviceToDevice, stream);
        scatter<<<(n_edges + 255) / 256, 256, 0, stream>>>(u_idx, i_idx, ui_vals, iu_vals,
                                                           cur_u, cur_i, iC, vC, uC, wC, n_edges);

        // ---- 4 gather SPMMs (self*d fused) ----
        int ub = (USER_NUM * 64 + 255) / 256;
        int ib = (ITEM_NUM * 64 + 255) / 256;
        csr_spmm<<<ub, 256, 0, stream>>>(ptr_u, iC, vC, ei,  eu,  d_i, g1u, USER_NUM);
        csr_spmm<<<ib, 256, 0, stream>>>(ptr_i, uC, wC, eu,  ei,  d_j, g1i, ITEM_NUM);
        csr_spmm<<<ub, 256, 0, stream>>>(ptr_u, iC, vC, g1i, g1u, d_i, g2u, USER_NUM);
        csr_spmm<<<ib, 256, 0, stream>>>(ptr_i, uC, wC, g1u, g1i, d_j, g2i, ITEM_NUM);
    } else {
        // ---- fallback: atomic scatter path (fits in 77MB) ----
        long long tot = (long long)n_edges * 16;
        int eblocks = (int)((tot + 255) / 256);
        init_scale<<<(USER_NUM * 16 + 255) / 256, 256, 0, stream>>>(eu, d_i, g1u, USER_NUM);
        init_scale<<<(ITEM_NUM * 16 + 255) / 256, 256, 0, stream>>>(ei, d_j, g1i, ITEM_NUM);
        edge_spmm<<<eblocks, 256, 0, stream>>>(eu, ei, g1u, g1i, u_idx, i_idx, ui_vals, iu_vals, n_edges);
        init_scale<<<(USER_NUM * 16 + 255) / 256, 256, 0, stream>>>(g1u, d_i, g2u, USER_NUM);
        init_scale<<<(ITEM_NUM * 16 + 255) / 256, 256, 0, stream>>>(g1i, d_j, g2i, ITEM_NUM);
        edge_spmm<<<eblocks, 256, 0, stream>>>(g1u, g1i, g2u, g2i, u_idx, i_idx, ui_vals, iu_vals, n_edges);
    }

    batch_loss<<<(batch * 64 + 255) / 256, 256, 0, stream>>>(eu, ei, g1u, g1i, g2u, g2i,
                                                             user, item_i, item_j, acc, batch);
    finalize<<<1, 64, 0, stream>>>(acc, out, batch);
}

// Round 4
// 1452.512 us; speedup vs baseline: 7.5904x; 1.5641x over previous
//
#include <hip/hip_runtime.h>
#include <math.h>

#define USER_NUM 100000
#define ITEM_NUM 50000
#define FACTOR   64
#define LAMADA   0.0001f

// ---------------- CSR build ----------------

__global__ void histogram(const int* __restrict__ u_idx, const int* __restrict__ i_idx,
                          int* __restrict__ cnt_u, int* __restrict__ cnt_i, int n_edges) {
    int e = blockIdx.x * blockDim.x + threadIdx.x;
    if (e >= n_edges) return;
    atomicAdd(&cnt_u[u_idx[e]], 1);
    atomicAdd(&cnt_i[i_idx[e]], 1);
}

// Phase 1: per-256-block exclusive scan; block totals to partials.
__global__ void scan1(const int* __restrict__ cnt, int* __restrict__ excl,
                      int* __restrict__ partials, int n) {
    __shared__ int s[256];
    int tid = threadIdx.x;
    int idx = blockIdx.x * 256 + tid;
    int x = (idx < n) ? cnt[idx] : 0;
    s[tid] = x;
    __syncthreads();
    for (int off = 1; off < 256; off <<= 1) {
        int t = (tid >= off) ? s[tid - off] : 0;
        __syncthreads();
        s[tid] += t;
        __syncthreads();
    }
    if (idx < n) excl[idx] = s[tid] - x;
    if (tid == 255) partials[blockIdx.x] = s[255];
}

// Phase 2: single block scans <=512 partials (exclusive) and writes grand total.
__global__ void scan2(int* __restrict__ partials, int n, int* __restrict__ total_out) {
    __shared__ int s[512];
    int tid = threadIdx.x;
    int x = (tid < n) ? partials[tid] : 0;
    s[tid] = x;
    __syncthreads();
    for (int off = 1; off < 512; off <<= 1) {
        int t = (tid >= off) ? s[tid - off] : 0;
        __syncthreads();
        s[tid] += t;
        __syncthreads();
    }
    if (tid < n) partials[tid] = s[tid] - x;
    if (tid == 511) *total_out = s[511];
}

// Phase 3: add block offsets; write both ptr (persistent) and cur (scatter cursors).
__global__ void scan3(int* __restrict__ excl, const int* __restrict__ partials,
                      int* __restrict__ cur, int n) {
    int idx = blockIdx.x * blockDim.x + threadIdx.x;
    if (idx >= n) return;
    int v = excl[idx] + partials[idx >> 8];
    excl[idx] = v;
    cur[idx] = v;
}

// Scatter edges into both sorted orders; packed (col, val_bits) 8B stores.
__global__ void scatter2(const int* __restrict__ u_idx, const int* __restrict__ i_idx,
                         const float* __restrict__ ui_vals, const float* __restrict__ iu_vals,
                         int* __restrict__ cur_u, int* __restrict__ cur_i,
                         int2* __restrict__ cs_u, int2* __restrict__ cs_i, int n_edges) {
    int e = blockIdx.x * blockDim.x + threadIdx.x;
    if (e >= n_edges) return;
    int u = u_idx[e], i = i_idx[e];
    int pu = atomicAdd(&cur_u[u], 1);
    cs_u[pu] = make_int2(i, __float_as_int(ui_vals[e]));
    int pi = atomicAdd(&cur_i[i], 1);
    cs_i[pi] = make_int2(u, __float_as_int(iu_vals[e]));
}

// ---------------- gather SPMM (layer 1, full tables) ----------------
// out[r,:] = self[r,:]*d[r] + sum_k val[k]*src[col[k],:]   one wave per row.
__global__ void csr_spmm_p(const int* __restrict__ ptr, const int2* __restrict__ cs,
                           const float* __restrict__ src, const float* __restrict__ self,
                           const float* __restrict__ d, float* __restrict__ out, int n_rows) {
    int w = (blockIdx.x * blockDim.x + threadIdx.x) >> 6;
    int lane = threadIdx.x & 63;
    if (w >= n_rows) return;
    int start = ptr[w], end = ptr[w + 1];
    float acc = self[(size_t)w * FACTOR + lane] * d[w];
    for (int k = start; k < end; ++k) {
        int2 ce = cs[k];
        acc += __int_as_float(ce.y) * src[(size_t)ce.x * FACTOR + lane];
    }
    out[(size_t)w * FACTOR + lane] = acc;
}

// ---------------- fused layer-2 + loss ----------------
// One wave per batch sample. Layer-2 rows computed on the fly (only batch rows
// are ever needed), then dot products + reduction terms.
__global__ void fused_batch(const float* __restrict__ eu, const float* __restrict__ ei,
                            const float* __restrict__ g1u, const float* __restrict__ g1i,
                            const int* __restrict__ ptr_u, const int2* __restrict__ cs_u,
                            const int* __restrict__ ptr_i, const int2* __restrict__ cs_i,
                            const float* __restrict__ d_i, const float* __restrict__ d_j,
                            const int* __restrict__ user, const int* __restrict__ item_i,
                            const int* __restrict__ item_j, float* __restrict__ acc, int batch) {
    int w = (blockIdx.x * blockDim.x + threadIdx.x) >> 6;
    int lane = threadIdx.x & 63;
    if (w >= batch) return;
    int uu = user[w], ii = item_i[w], jj = item_j[w];

    // gcn_u[uu] = eu + g1u + (sum ui_val*g1i[col] + g1u*d_i)
    size_t uo = (size_t)uu * FACTOR + lane;
    float g1 = g1u[uo];
    float l2 = g1 * d_i[uu];
    for (int k = ptr_u[uu], e = ptr_u[uu + 1]; k < e; ++k) {
        int2 ce = cs_u[k];
        l2 += __int_as_float(ce.y) * g1i[(size_t)ce.x * FACTOR + lane];
    }
    float U = eu[uo] + g1 + l2;

    // gcn_i[ii]
    size_t io = (size_t)ii * FACTOR + lane;
    float h1 = g1i[io];
    float m2 = h1 * d_j[ii];
    for (int k = ptr_i[ii], e = ptr_i[ii + 1]; k < e; ++k) {
        int2 ce = cs_i[k];
        m2 += __int_as_float(ce.y) * g1u[(size_t)ce.x * FACTOR + lane];
    }
    float Pi = ei[io] + h1 + m2;

    // gcn_i[jj]
    size_t jo = (size_t)jj * FACTOR + lane;
    float h1j = g1i[jo];
    float n2 = h1j * d_j[jj];
    for (int k = ptr_i[jj], e = ptr_i[jj + 1]; k < e; ++k) {
        int2 ce = cs_i[k];
        n2 += __int_as_float(ce.y) * g1u[(size_t)ce.x * FACTOR + lane];
    }
    float Pj = ei[jo] + h1j + n2;

    float di  = U * Pi;
    float dj  = U * Pj;
    float su2 = U * U;
    float sp2 = Pi * Pi + Pj * Pj;
    for (int off = 32; off; off >>= 1) {
        di  += __shfl_down(di,  off, 64);
        dj  += __shfl_down(dj,  off, 64);
        su2 += __shfl_down(su2, off, 64);
        sp2 += __shfl_down(sp2, off, 64);
    }
    if (lane == 0) {
        float x  = -(di - dj);
        float sp = fmaxf(x, 0.f) + log1pf(expf(-fabsf(x)));
        atomicAdd(acc + 0, su2);
        atomicAdd(acc + 1, sp2);
        atomicAdd(acc + 2, sp);
    }
}

__global__ void finalize(const float* __restrict__ acc, float* __restrict__ out, int batch) {
    if (threadIdx.x == 0 && blockIdx.x == 0) {
        float inv_b  = 1.0f / (float)batch;
        float inv_bf = 1.0f / (float)(batch * FACTOR);
        out[0] = acc[2] * inv_b + LAMADA * acc[0] * inv_bf + LAMADA * acc[1] * inv_bf;
    }
}

// ---------------- fallback (atomic) path ----------------

__global__ void init_scale(const float* __restrict__ src, const float* __restrict__ d,
                           float* __restrict__ dst, int n_rows) {
    int gid = blockIdx.x * blockDim.x + threadIdx.x;
    int total = n_rows * 16;
    if (gid >= total) return;
    int r = gid >> 4;
    float s = d[r];
    float4 v = ((const float4*)src)[gid];
    v.x *= s; v.y *= s; v.z *= s; v.w *= s;
    ((float4*)dst)[gid] = v;
}

__global__ void edge_spmm(const float* __restrict__ srcU, const float* __restrict__ srcI,
                          float* __restrict__ dstU, float* __restrict__ dstI,
                          const int* __restrict__ u_idx, const int* __restrict__ i_idx,
                          const float* __restrict__ ui_vals, const float* __restrict__ iu_vals,
                          int n_edges) {
    long long gid = (long long)blockIdx.x * blockDim.x + threadIdx.x;
    int e = (int)(gid >> 4);
    if (e >= n_edges) return;
    int sub = ((int)gid & 15) * 4;
    int u = u_idx[e], i = i_idx[e];
    float uv = ui_vals[e], iv = iu_vals[e];
    size_t uo = (size_t)u * FACTOR + sub;
    size_t io = (size_t)i * FACTOR + sub;
    float4 a = *(const float4*)(srcI + io);
    float4 b = *(const float4*)(srcU + uo);
    float* du = dstU + uo;
    float* di = dstI + io;
    atomicAdd(du + 0, a.x * uv); atomicAdd(du + 1, a.y * uv);
    atomicAdd(du + 2, a.z * uv); atomicAdd(du + 3, a.w * uv);
    atomicAdd(di + 0, b.x * iv); atomicAdd(di + 1, b.y * iv);
    atomicAdd(di + 2, b.z * iv); atomicAdd(di + 3, b.w * iv);
}

__global__ void batch_loss(const float* __restrict__ eu, const float* __restrict__ ei,
                           const float* __restrict__ g1u, const float* __restrict__ g1i,
                           const float* __restrict__ g2u, const float* __restrict__ g2i,
                           const int* __restrict__ user, const int* __restrict__ item_i,
                           const int* __restrict__ item_j, float* __restrict__ acc, int batch) {
    int gid = blockIdx.x * blockDim.x + threadIdx.x;
    int w = gid >> 6;
    int lane = threadIdx.x & 63;
    if (w >= batch) return;
    int uu = user[w], ii = item_i[w], jj = item_j[w];
    size_t uo = (size_t)uu * FACTOR + lane;
    size_t io = (size_t)ii * FACTOR + lane;
    size_t jo = (size_t)jj * FACTOR + lane;
    float uvv = eu[uo] + g1u[uo] + g2u[uo];
    float piv = ei[io] + g1i[io] + g2i[io];
    float pjv = ei[jo] + g1i[jo] + g2i[jo];
    float di  = uvv * piv;
    float dj  = uvv * pjv;
    float su2 = uvv * uvv;
    float sp2 = piv * piv + pjv * pjv;
    for (int off = 32; off; off >>= 1) {
        di  += __shfl_down(di,  off, 64);
        dj  += __shfl_down(dj,  off, 64);
        su2 += __shfl_down(su2, off, 64);
        sp2 += __shfl_down(sp2, off, 64);
    }
    if (lane == 0) {
        float x  = -(di - dj);
        float sp = fmaxf(x, 0.f) + log1pf(expf(-fabsf(x)));
        atomicAdd(acc + 0, su2);
        atomicAdd(acc + 1, sp2);
        atomicAdd(acc + 2, sp);
    }
}

extern "C" void kernel_launch(void* const* d_in, const int* in_sizes, int n_in,
                              void* d_out, int out_size, void* d_ws, size_t ws_size,
                              hipStream_t stream) {
    const float* eu      = (const float*)d_in[0];
    const float* ei      = (const float*)d_in[1];
    const int*   u_idx   = (const int*)d_in[2];
    const int*   i_idx   = (const int*)d_in[3];
    const float* ui_vals = (const float*)d_in[4];
    const float* iu_vals = (const float*)d_in[5];
    const float* d_i     = (const float*)d_in[6];
    const float* d_j     = (const float*)d_in[7];
    const int*   user    = (const int*)d_in[8];
    const int*   item_i  = (const int*)d_in[9];
    const int*   item_j  = (const int*)d_in[10];
    int n_edges = in_sizes[2];
    int batch   = in_sizes[8];
    float* out  = (float*)d_out;

    const size_t FU = (size_t)USER_NUM * FACTOR;
    const size_t FI = (size_t)ITEM_NUM * FACTOR;
    const size_t NE = (size_t)n_edges;

    // Workspace layout (words)
    float* ws    = (float*)d_ws;
    float* g1u   = ws;                          // FU
    float* g1i   = g1u + FU;                    // FI
    int2*  cs_u  = (int2*)(g1i + FI);           // NE int2 (8B-aligned: FU+FI even)
    int2*  cs_i  = cs_u + NE;                   // NE int2
    int*   cnt_u = (int*)(cs_i + NE);           // USER_NUM
    int*   cnt_i = cnt_u + USER_NUM;            // ITEM_NUM   (adjacent: one memset)
    int*   ptr_u = cnt_i + ITEM_NUM;            // USER_NUM+1
    int*   ptr_i = ptr_u + (USER_NUM + 1);      // ITEM_NUM+1
    int*   cur_u = ptr_i + (ITEM_NUM + 1);      // USER_NUM
    int*   cur_i = cur_u + USER_NUM;            // ITEM_NUM
    int*   prt_u = cur_i + ITEM_NUM;            // 512 partials
    int*   prt_i = prt_u + 512;                 // 512 partials
    float* acc   = (float*)(prt_i + 512);       // 4

    size_t need_bytes = ((size_t)(acc + 4) - (size_t)d_ws);

    hipMemsetAsync(acc, 0, 4 * sizeof(float), stream);

    if (ws_size >= need_bytes) {
        const int nbu = (USER_NUM + 255) / 256;   // 391
        const int nbi = (ITEM_NUM + 255) / 256;   // 196

        hipMemsetAsync(cnt_u, 0, (size_t)(USER_NUM + ITEM_NUM) * sizeof(int), stream);
        histogram<<<(n_edges + 255) / 256, 256, 0, stream>>>(u_idx, i_idx, cnt_u, cnt_i, n_edges);

        scan1<<<nbu, 256, 0, stream>>>(cnt_u, ptr_u, prt_u, USER_NUM);
        scan1<<<nbi, 256, 0, stream>>>(cnt_i, ptr_i, prt_i, ITEM_NUM);
        scan2<<<1, 512, 0, stream>>>(prt_u, nbu, ptr_u + USER_NUM);
        scan2<<<1, 512, 0, stream>>>(prt_i, nbi, ptr_i + ITEM_NUM);
        scan3<<<nbu, 256, 0, stream>>>(ptr_u, prt_u, cur_u, USER_NUM);
        scan3<<<nbi, 256, 0, stream>>>(ptr_i, prt_i, cur_i, ITEM_NUM);

        scatter2<<<(n_edges + 255) / 256, 256, 0, stream>>>(u_idx, i_idx, ui_vals, iu_vals,
                                                            cur_u, cur_i, cs_u, cs_i, n_edges);

        // Layer 1 (full tables, needed as layer-2 gather sources)
        csr_spmm_p<<<(USER_NUM * 64 + 255) / 256, 256, 0, stream>>>(ptr_u, cs_u, ei, eu, d_i, g1u, USER_NUM);
        csr_spmm_p<<<(ITEM_NUM * 64 + 255) / 256, 256, 0, stream>>>(ptr_i, cs_i, eu, ei, d_j, g1i, ITEM_NUM);

        // Layer 2 only at batch rows, fused with loss
        fused_batch<<<(batch * 64 + 255) / 256, 256, 0, stream>>>(eu, ei, g1u, g1i,
                                                                  ptr_u, cs_u, ptr_i, cs_i,
                                                                  d_i, d_j, user, item_i, item_j,
                                                                  acc, batch);
    } else {
        // Fallback: atomic scatter path (needs only 77MB)
        float* f_g1u = ws;
        float* f_g1i = f_g1u + FU;
        float* f_g2u = f_g1i + FI;
        float* f_g2i = f_g2u + FU;
        float* f_acc = f_g2i + FI;
        hipMemsetAsync(f_acc, 0, 4 * sizeof(float), stream);
        long long tot = (long long)n_edges * 16;
        int eblocks = (int)((tot + 255) / 256);
        init_scale<<<(USER_NUM * 16 + 255) / 256, 256, 0, stream>>>(eu, d_i, f_g1u, USER_NUM);
        init_scale<<<(ITEM_NUM * 16 + 255) / 256, 256, 0, stream>>>(ei, d_j, f_g1i, ITEM_NUM);
        edge_spmm<<<eblocks, 256, 0, stream>>>(eu, ei, f_g1u, f_g1i, u_idx, i_idx, ui_vals, iu_vals, n_edges);
        init_scale<<<(USER_NUM * 16 + 255) / 256, 256, 0, stream>>>(f_g1u, d_i, f_g2u, USER_NUM);
        init_scale<<<(ITEM_NUM * 16 + 255) / 256, 256, 0, stream>>>(f_g1i, d_j, f_g2i, ITEM_NUM);
        edge_spmm<<<eblocks, 256, 0, stream>>>(f_g1u, f_g1i, f_g2u, f_g2i, u_idx, i_idx, ui_vals, iu_vals, n_edges);
        batch_loss<<<(batch * 64 + 255) / 256, 256, 0, stream>>>(eu, ei, f_g1u, f_g1i, f_g2u, f_g2i,
                                                                 user, item_i, item_j, f_acc, batch);
        finalize<<<1, 64, 0, stream>>>(f_acc, out, batch);
        return;
    }

    finalize<<<1, 64, 0, stream>>>(acc, out, batch);
}

// Round 5
// 1235.225 us; speedup vs baseline: 8.9257x; 1.1759x over previous
//
#include <hip/hip_runtime.h>
#include <math.h>

#define USER_NUM 100000
#define ITEM_NUM 50000
#define FACTOR   64
#define LAMADA   0.0001f

// Bucketed counting sort parameters: 256 rows per bucket.
#define NBU  391      // ceil(100000/256)
#define NBI  196      // ceil(50000/256)
#define CAPU 10240    // mean 8192, sigma~90  -> 22 sigma slack
#define CAPI 18432    // mean 16384, sigma~128 -> 16 sigma slack
#define CHUNK 8192    // edges per partition block

// ---------------- build: init cursors + acc ----------------
__global__ void init_cursors(int* __restrict__ cur_u, int* __restrict__ cur_i,
                             float* __restrict__ acc) {
    int t = blockIdx.x * blockDim.x + threadIdx.x;
    if (t < NBU) cur_u[t] = t * CAPU;
    if (t < NBI) cur_i[t] = t * CAPI;
    if (t < 4) acc[t] = 0.f;
}

// ---------------- build: K1 partition edges into buckets (edge-id staging) ----
__global__ void partition(const int* __restrict__ u_idx, const int* __restrict__ i_idx,
                          int* __restrict__ cur_u, int* __restrict__ cur_i,
                          int* __restrict__ staged_u, int* __restrict__ staged_i,
                          int n_edges) {
    __shared__ int s_u[NBU];
    __shared__ int s_i[NBI];
    int tid = threadIdx.x;
    for (int b = tid; b < NBU; b += 256) s_u[b] = 0;
    for (int b = tid; b < NBI; b += 256) s_i[b] = 0;
    __syncthreads();
    int start = blockIdx.x * CHUNK;
    int end   = min(start + CHUNK, n_edges);
    for (int e = start + tid; e < end; e += 256) {
        atomicAdd(&s_u[u_idx[e] >> 8], 1);
        atomicAdd(&s_i[i_idx[e] >> 8], 1);
    }
    __syncthreads();
    // block-local count -> global append base per bucket
    for (int b = tid; b < NBU; b += 256) {
        int c = s_u[b];
        s_u[b] = c ? atomicAdd(&cur_u[b], c) : 0;
    }
    for (int b = tid; b < NBI; b += 256) {
        int c = s_i[b];
        s_i[b] = c ? atomicAdd(&cur_i[b], c) : 0;
    }
    __syncthreads();
    for (int e = start + tid; e < end; e += 256) {
        int pu = atomicAdd(&s_u[u_idx[e] >> 8], 1);
        staged_u[pu] = e;
        int pi = atomicAdd(&s_i[i_idx[e] >> 8], 1);
        staged_i[pi] = e;
    }
}

// ---------------- build: bucket bases (tiny scans) ----------------
__global__ void bucket_base(const int* __restrict__ cur_u, const int* __restrict__ cur_i,
                            int* __restrict__ bb_u, int* __restrict__ bb_i,
                            int* __restrict__ ptr_u_end, int* __restrict__ ptr_i_end,
                            int n_edges) {
    __shared__ int s[512];
    int tid = threadIdx.x;
    int cu = (tid < NBU) ? (cur_u[tid] - tid * CAPU) : 0;
    s[tid] = cu; __syncthreads();
    for (int off = 1; off < 512; off <<= 1) {
        int t = (tid >= off) ? s[tid - off] : 0;
        __syncthreads(); s[tid] += t; __syncthreads();
    }
    if (tid < NBU) bb_u[tid] = s[tid] - cu;
    __syncthreads();
    int ci = (tid < NBI) ? (cur_i[tid] - tid * CAPI) : 0;
    s[tid] = ci; __syncthreads();
    for (int off = 1; off < 512; off <<= 1) {
        int t = (tid >= off) ? s[tid - off] : 0;
        __syncthreads(); s[tid] += t; __syncthreads();
    }
    if (tid < NBI) bb_i[tid] = s[tid] - ci;
    if (tid == 0) { *ptr_u_end = n_edges; *ptr_i_end = n_edges; }
}

// ---------------- build: K2 per-bucket finalize (ptr + CSR placement) -------
// One block per bucket (256 rows). All randomness stays in LDS / bucket-local
// L2-resident regions.
__global__ void bucket_finalize(const int* __restrict__ staged, const int* __restrict__ cur,
                                const int* __restrict__ bbase, int cap,
                                const int* __restrict__ row_idx, const int* __restrict__ col_idx,
                                const float* __restrict__ vals,
                                int* __restrict__ ptr, int2* __restrict__ cs, int n_rows) {
    __shared__ int s_cnt[256];
    __shared__ int s_pos[256];
    int b = blockIdx.x, tid = threadIdx.x;
    int sbase = b * cap;
    int nE = cur[b] - sbase;
    int rbase = b << 8;
    s_cnt[tid] = 0;
    __syncthreads();
    for (int k = tid; k < nE; k += 256) {
        int eid = staged[sbase + k];
        atomicAdd(&s_cnt[row_idx[eid] & 255], 1);
    }
    __syncthreads();
    int x = s_cnt[tid];
    s_pos[tid] = x; __syncthreads();
    for (int off = 1; off < 256; off <<= 1) {
        int t = (tid >= off) ? s_pos[tid - off] : 0;
        __syncthreads(); s_pos[tid] += t; __syncthreads();
    }
    int excl = s_pos[tid] - x + bbase[b];    // global CSR offset of row rbase+tid
    int r = rbase + tid;
    if (r < n_rows) ptr[r] = excl;
    s_pos[tid] = excl;                        // reuse as global-position cursor
    __syncthreads();
    for (int k = tid; k < nE; k += 256) {
        int eid = staged[sbase + k];
        int rl = row_idx[eid] & 255;
        int pos = atomicAdd(&s_pos[rl], 1);
        cs[pos] = make_int2(col_idx[eid], __float_as_int(vals[eid]));
    }
}

// ---------------- gather SPMM (layer 1) ----------------
__global__ void csr_spmm_p(const int* __restrict__ ptr, const int2* __restrict__ cs,
                           const float* __restrict__ src, const float* __restrict__ self,
                           const float* __restrict__ d, float* __restrict__ out, int n_rows) {
    int w = (blockIdx.x * blockDim.x + threadIdx.x) >> 6;
    int lane = threadIdx.x & 63;
    if (w >= n_rows) return;
    int start = ptr[w], end = ptr[w + 1];
    float acc = self[(size_t)w * FACTOR + lane] * d[w];
    for (int k = start; k < end; ++k) {
        int2 ce = cs[k];
        acc += __int_as_float(ce.y) * src[(size_t)ce.x * FACTOR + lane];
    }
    out[(size_t)w * FACTOR + lane] = acc;
}

// ---------------- fused layer-2 + loss ----------------
__global__ void fused_batch(const float* __restrict__ eu, const float* __restrict__ ei,
                            const float* __restrict__ g1u, const float* __restrict__ g1i,
                            const int* __restrict__ ptr_u, const int2* __restrict__ cs_u,
                            const int* __restrict__ ptr_i, const int2* __restrict__ cs_i,
                            const float* __restrict__ d_i, const float* __restrict__ d_j,
                            const int* __restrict__ user, const int* __restrict__ item_i,
                            const int* __restrict__ item_j, float* __restrict__ acc, int batch) {
    int w = (blockIdx.x * blockDim.x + threadIdx.x) >> 6;
    int lane = threadIdx.x & 63;
    if (w >= batch) return;
    int uu = user[w], ii = item_i[w], jj = item_j[w];

    size_t uo = (size_t)uu * FACTOR + lane;
    float g1 = g1u[uo];
    float l2 = g1 * d_i[uu];
    for (int k = ptr_u[uu], e = ptr_u[uu + 1]; k < e; ++k) {
        int2 ce = cs_u[k];
        l2 += __int_as_float(ce.y) * g1i[(size_t)ce.x * FACTOR + lane];
    }
    float U = eu[uo] + g1 + l2;

    size_t io = (size_t)ii * FACTOR + lane;
    float h1 = g1i[io];
    float m2 = h1 * d_j[ii];
    for (int k = ptr_i[ii], e = ptr_i[ii + 1]; k < e; ++k) {
        int2 ce = cs_i[k];
        m2 += __int_as_float(ce.y) * g1u[(size_t)ce.x * FACTOR + lane];
    }
    float Pi = ei[io] + h1 + m2;

    size_t jo = (size_t)jj * FACTOR + lane;
    float h1j = g1i[jo];
    float n2 = h1j * d_j[jj];
    for (int k = ptr_i[jj], e = ptr_i[jj + 1]; k < e; ++k) {
        int2 ce = cs_i[k];
        n2 += __int_as_float(ce.y) * g1u[(size_t)ce.x * FACTOR + lane];
    }
    float Pj = ei[jo] + h1j + n2;

    float di  = U * Pi;
    float dj  = U * Pj;
    float su2 = U * U;
    float sp2 = Pi * Pi + Pj * Pj;
    for (int off = 32; off; off >>= 1) {
        di  += __shfl_down(di,  off, 64);
        dj  += __shfl_down(dj,  off, 64);
        su2 += __shfl_down(su2, off, 64);
        sp2 += __shfl_down(sp2, off, 64);
    }
    if (lane == 0) {
        float x  = -(di - dj);
        float sp = fmaxf(x, 0.f) + log1pf(expf(-fabsf(x)));
        atomicAdd(acc + 0, su2);
        atomicAdd(acc + 1, sp2);
        atomicAdd(acc + 2, sp);
    }
}

__global__ void finalize(const float* __restrict__ acc, float* __restrict__ out, int batch) {
    if (threadIdx.x == 0 && blockIdx.x == 0) {
        float inv_b  = 1.0f / (float)batch;
        float inv_bf = 1.0f / (float)(batch * FACTOR);
        out[0] = acc[2] * inv_b + LAMADA * acc[0] * inv_bf + LAMADA * acc[1] * inv_bf;
    }
}

// ---------------- fallback (atomic) path ----------------
__global__ void init_scale(const float* __restrict__ src, const float* __restrict__ d,
                           float* __restrict__ dst, int n_rows) {
    int gid = blockIdx.x * blockDim.x + threadIdx.x;
    int total = n_rows * 16;
    if (gid >= total) return;
    int r = gid >> 4;
    float s = d[r];
    float4 v = ((const float4*)src)[gid];
    v.x *= s; v.y *= s; v.z *= s; v.w *= s;
    ((float4*)dst)[gid] = v;
}

__global__ void edge_spmm(const float* __restrict__ srcU, const float* __restrict__ srcI,
                          float* __restrict__ dstU, float* __restrict__ dstI,
                          const int* __restrict__ u_idx, const int* __restrict__ i_idx,
                          const float* __restrict__ ui_vals, const float* __restrict__ iu_vals,
                          int n_edges) {
    long long gid = (long long)blockIdx.x * blockDim.x + threadIdx.x;
    int e = (int)(gid >> 4);
    if (e >= n_edges) return;
    int sub = ((int)gid & 15) * 4;
    int u = u_idx[e], i = i_idx[e];
    float uv = ui_vals[e], iv = iu_vals[e];
    size_t uo = (size_t)u * FACTOR + sub;
    size_t io = (size_t)i * FACTOR + sub;
    float4 a = *(const float4*)(srcI + io);
    float4 b = *(const float4*)(srcU + uo);
    float* du = dstU + uo;
    float* di = dstI + io;
    atomicAdd(du + 0, a.x * uv); atomicAdd(du + 1, a.y * uv);
    atomicAdd(du + 2, a.z * uv); atomicAdd(du + 3, a.w * uv);
    atomicAdd(di + 0, b.x * iv); atomicAdd(di + 1, b.y * iv);
    atomicAdd(di + 2, b.z * iv); atomicAdd(di + 3, b.w * iv);
}

__global__ void batch_loss(const float* __restrict__ eu, const float* __restrict__ ei,
                           const float* __restrict__ g1u, const float* __restrict__ g1i,
                           const float* __restrict__ g2u, const float* __restrict__ g2i,
                           const int* __restrict__ user, const int* __restrict__ item_i,
                           const int* __restrict__ item_j, float* __restrict__ acc, int batch) {
    int gid = blockIdx.x * blockDim.x + threadIdx.x;
    int w = gid >> 6;
    int lane = threadIdx.x & 63;
    if (w >= batch) return;
    int uu = user[w], ii = item_i[w], jj = item_j[w];
    size_t uo = (size_t)uu * FACTOR + lane;
    size_t io = (size_t)ii * FACTOR + lane;
    size_t jo = (size_t)jj * FACTOR + lane;
    float uvv = eu[uo] + g1u[uo] + g2u[uo];
    float piv = ei[io] + g1i[io] + g2i[io];
    float pjv = ei[jo] + g1i[jo] + g2i[jo];
    float di  = uvv * piv;
    float dj  = uvv * pjv;
    float su2 = uvv * uvv;
    float sp2 = piv * piv + pjv * pjv;
    for (int off = 32; off; off >>= 1) {
        di  += __shfl_down(di,  off, 64);
        dj  += __shfl_down(dj,  off, 64);
        su2 += __shfl_down(su2, off, 64);
        sp2 += __shfl_down(sp2, off, 64);
    }
    if (lane == 0) {
        float x  = -(di - dj);
        float sp = fmaxf(x, 0.f) + log1pf(expf(-fabsf(x)));
        atomicAdd(acc + 0, su2);
        atomicAdd(acc + 1, sp2);
        atomicAdd(acc + 2, sp);
    }
}

extern "C" void kernel_launch(void* const* d_in, const int* in_sizes, int n_in,
                              void* d_out, int out_size, void* d_ws, size_t ws_size,
                              hipStream_t stream) {
    const float* eu      = (const float*)d_in[0];
    const float* ei      = (const float*)d_in[1];
    const int*   u_idx   = (const int*)d_in[2];
    const int*   i_idx   = (const int*)d_in[3];
    const float* ui_vals = (const float*)d_in[4];
    const float* iu_vals = (const float*)d_in[5];
    const float* d_i     = (const float*)d_in[6];
    const float* d_j     = (const float*)d_in[7];
    const int*   user    = (const int*)d_in[8];
    const int*   item_i  = (const int*)d_in[9];
    const int*   item_j  = (const int*)d_in[10];
    int n_edges = in_sizes[2];
    int batch   = in_sizes[8];
    float* out  = (float*)d_out;

    const size_t FU = (size_t)USER_NUM * FACTOR;
    const size_t FI = (size_t)ITEM_NUM * FACTOR;
    const size_t NE = (size_t)n_edges;

    // Workspace layout. Staging (edge-ids) overlays g1u/g1i: staging is dead
    // before csr_spmm writes g1u/g1i (sequential stream ordering makes this safe).
    float* ws    = (float*)d_ws;
    float* g1u   = ws;                              // FU floats
    float* g1i   = g1u + FU;                        // FI floats
    int*   staged_u = (int*)g1u;                    // NBU*CAPU ints (16.0MB)
    int*   staged_i = staged_u + (size_t)NBU * CAPU; // NBI*CAPI ints (14.5MB) — fits in FU+FI
    int2*  cs_u  = (int2*)(g1i + FI);               // NE
    int2*  cs_i  = cs_u + NE;                       // NE
    int*   ptr_u = (int*)(cs_i + NE);               // USER_NUM+1
    int*   ptr_i = ptr_u + (USER_NUM + 1);          // ITEM_NUM+1
    int*   cur_u = ptr_i + (ITEM_NUM + 1);          // NBU
    int*   cur_i = cur_u + NBU;                     // NBI
    int*   bb_u  = cur_i + NBI;                     // NBU
    int*   bb_i  = bb_u + NBU;                      // NBI
    float* acc   = (float*)(bb_i + NBI);            // 4

    size_t need_bytes = ((size_t)(acc + 4) - (size_t)d_ws);

    if (ws_size >= need_bytes) {
        // ---- build: bucketed counting sort, both directions ----
        init_cursors<<<1, 512, 0, stream>>>(cur_u, cur_i, acc);
        int nb1 = (n_edges + CHUNK - 1) / CHUNK;
        partition<<<nb1, 256, 0, stream>>>(u_idx, i_idx, cur_u, cur_i,
                                           staged_u, staged_i, n_edges);
        bucket_base<<<1, 512, 0, stream>>>(cur_u, cur_i, bb_u, bb_i,
                                           ptr_u + USER_NUM, ptr_i + ITEM_NUM, n_edges);
        bucket_finalize<<<NBU, 256, 0, stream>>>(staged_u, cur_u, bb_u, CAPU,
                                                 u_idx, i_idx, ui_vals, ptr_u, cs_u, USER_NUM);
        bucket_finalize<<<NBI, 256, 0, stream>>>(staged_i, cur_i, bb_i, CAPI,
                                                 i_idx, u_idx, iu_vals, ptr_i, cs_i, ITEM_NUM);

        // ---- layer 1 (full tables) ----
        csr_spmm_p<<<(USER_NUM * 64 + 255) / 256, 256, 0, stream>>>(ptr_u, cs_u, ei, eu, d_i, g1u, USER_NUM);
        csr_spmm_p<<<(ITEM_NUM * 64 + 255) / 256, 256, 0, stream>>>(ptr_i, cs_i, eu, ei, d_j, g1i, ITEM_NUM);

        // ---- layer 2 @ batch rows, fused with loss ----
        fused_batch<<<(batch * 64 + 255) / 256, 256, 0, stream>>>(eu, ei, g1u, g1i,
                                                                  ptr_u, cs_u, ptr_i, cs_i,
                                                                  d_i, d_j, user, item_i, item_j,
                                                                  acc, batch);
        finalize<<<1, 64, 0, stream>>>(acc, out, batch);
    } else {
        // ---- fallback: atomic scatter path (77MB) ----
        float* f_g1u = ws;
        float* f_g1i = f_g1u + FU;
        float* f_g2u = f_g1i + FI;
        float* f_g2i = f_g2u + FU;
        float* f_acc = f_g2i + FI;
        hipMemsetAsync(f_acc, 0, 4 * sizeof(float), stream);
        long long tot = (long long)n_edges * 16;
        int eblocks = (int)((tot + 255) / 256);
        init_scale<<<(USER_NUM * 16 + 255) / 256, 256, 0, stream>>>(eu, d_i, f_g1u, USER_NUM);
        init_scale<<<(ITEM_NUM * 16 + 255) / 256, 256, 0, stream>>>(ei, d_j, f_g1i, ITEM_NUM);
        edge_spmm<<<eblocks, 256, 0, stream>>>(eu, ei, f_g1u, f_g1i, u_idx, i_idx, ui_vals, iu_vals, n_edges);
        init_scale<<<(USER_NUM * 16 + 255) / 256, 256, 0, stream>>>(f_g1u, d_i, f_g2u, USER_NUM);
        init_scale<<<(ITEM_NUM * 16 + 255) / 256, 256, 0, stream>>>(f_g1i, d_j, f_g2i, ITEM_NUM);
        edge_spmm<<<eblocks, 256, 0, stream>>>(f_g1u, f_g1i, f_g2u, f_g2i, u_idx, i_idx, ui_vals, iu_vals, n_edges);
        batch_loss<<<(batch * 64 + 255) / 256, 256, 0, stream>>>(eu, ei, f_g1u, f_g1i, f_g2u, f_g2i,
                                                                 user, item_i, item_j, f_acc, batch);
        finalize<<<1, 64, 0, stream>>>(f_acc, out, batch);
    }
}

// Round 6
// 772.891 us; speedup vs baseline: 14.2649x; 1.5982x over previous
//
#include <hip/hip_runtime.h>
#include <math.h>

#define USER_NUM 100000
#define ITEM_NUM 50000
#define FACTOR   64
#define LAMADA   0.0001f

#define NBU   391     // ceil(100000/256) buckets of 256 user rows
#define NBI   196     // ceil(50000/256)  buckets of 256 item rows
#define CHUNK 8192    // edges per partition block

// ---------------- build: per-block bucket count -> global counters ----------
__global__ void count_buckets(const int* __restrict__ u_idx, const int* __restrict__ i_idx,
                              int* __restrict__ cnt_u, int* __restrict__ cnt_i, int n_edges) {
    __shared__ int s_u[NBU];
    __shared__ int s_i[NBI];
    int tid = threadIdx.x;
    for (int b = tid; b < NBU; b += 256) s_u[b] = 0;
    for (int b = tid; b < NBI; b += 256) s_i[b] = 0;
    __syncthreads();
    int start = blockIdx.x * CHUNK, end = min(start + CHUNK, n_edges);
    for (int e = start + tid; e < end; e += 256) {
        atomicAdd(&s_u[u_idx[e] >> 8], 1);
        atomicAdd(&s_i[i_idx[e] >> 8], 1);
    }
    __syncthreads();
    for (int b = tid; b < NBU; b += 256) { int c = s_u[b]; if (c) atomicAdd(&cnt_u[b], c); }
    for (int b = tid; b < NBI; b += 256) { int c = s_i[b]; if (c) atomicAdd(&cnt_i[b], c); }
}

// ---------------- build: scan bucket totals -> exact bases + cursors --------
__global__ void bucket_scan(const int* __restrict__ cnt_u, const int* __restrict__ cnt_i,
                            int* __restrict__ base_u, int* __restrict__ base_i,
                            int* __restrict__ cur_u, int* __restrict__ cur_i,
                            int* __restrict__ ptr_u_end, int* __restrict__ ptr_i_end,
                            int n_edges) {
    __shared__ int s[512];
    int tid = threadIdx.x;
    int x = (tid < NBU) ? cnt_u[tid] : 0;
    s[tid] = x; __syncthreads();
    for (int off = 1; off < 512; off <<= 1) {
        int t = (tid >= off) ? s[tid - off] : 0;
        __syncthreads(); s[tid] += t; __syncthreads();
    }
    if (tid < NBU) { int b = s[tid] - x; base_u[tid] = b; cur_u[tid] = b; }
    if (tid == 511) { base_u[NBU] = s[511]; *ptr_u_end = n_edges; }
    __syncthreads();
    int y = (tid < NBI) ? cnt_i[tid] : 0;
    s[tid] = y; __syncthreads();
    for (int off = 1; off < 512; off <<= 1) {
        int t = (tid >= off) ? s[tid - off] : 0;
        __syncthreads(); s[tid] += t; __syncthreads();
    }
    if (tid < NBI) { int b = s[tid] - y; base_i[tid] = b; cur_i[tid] = b; }
    if (tid == 511) { base_i[NBI] = s[511]; *ptr_i_end = n_edges; }
}

// ---------------- build: place packed (rowlocal<<20|col, val) into staging --
__global__ void place(const int* __restrict__ u_idx, const int* __restrict__ i_idx,
                      const float* __restrict__ ui_vals, const float* __restrict__ iu_vals,
                      int* __restrict__ cur_u, int* __restrict__ cur_i,
                      int2* __restrict__ staged_u, int2* __restrict__ staged_i, int n_edges) {
    __shared__ int s_u[NBU];
    __shared__ int s_i[NBI];
    int tid = threadIdx.x;
    for (int b = tid; b < NBU; b += 256) s_u[b] = 0;
    for (int b = tid; b < NBI; b += 256) s_i[b] = 0;
    __syncthreads();
    int start = blockIdx.x * CHUNK, end = min(start + CHUNK, n_edges);
    for (int e = start + tid; e < end; e += 256) {
        atomicAdd(&s_u[u_idx[e] >> 8], 1);
        atomicAdd(&s_i[i_idx[e] >> 8], 1);
    }
    __syncthreads();
    for (int b = tid; b < NBU; b += 256) { int c = s_u[b]; s_u[b] = c ? atomicAdd(&cur_u[b], c) : 0; }
    for (int b = tid; b < NBI; b += 256) { int c = s_i[b]; s_i[b] = c ? atomicAdd(&cur_i[b], c) : 0; }
    __syncthreads();
    for (int e = start + tid; e < end; e += 256) {
        int u = u_idx[e], i = i_idx[e];
        int pu = atomicAdd(&s_u[u >> 8], 1);
        staged_u[pu] = make_int2(((u & 255) << 20) | i, __float_as_int(ui_vals[e]));
        int pi = atomicAdd(&s_i[i >> 8], 1);
        staged_i[pi] = make_int2(((i & 255) << 20) | u, __float_as_int(iu_vals[e]));
    }
}

// ---------------- build: per-bucket finalize (ptr + CSR), no gathers --------
__global__ void bucket_finalize(const int2* __restrict__ staged, const int* __restrict__ base,
                                int* __restrict__ ptr, int2* __restrict__ cs, int n_rows) {
    __shared__ int s_cnt[256];
    __shared__ int s_pos[256];
    int b = blockIdx.x, tid = threadIdx.x;
    int sbase = base[b], nE = base[b + 1] - sbase;
    s_cnt[tid] = 0;
    __syncthreads();
    for (int k = tid; k < nE; k += 256) atomicAdd(&s_cnt[staged[sbase + k].x >> 20], 1);
    __syncthreads();
    int x = s_cnt[tid];
    s_pos[tid] = x; __syncthreads();
    for (int off = 1; off < 256; off <<= 1) {
        int t = (tid >= off) ? s_pos[tid - off] : 0;
        __syncthreads(); s_pos[tid] += t; __syncthreads();
    }
    int excl = s_pos[tid] - x + sbase;
    int r = (b << 8) + tid;
    if (r < n_rows) ptr[r] = excl;
    s_pos[tid] = excl;
    __syncthreads();
    for (int k = tid; k < nE; k += 256) {
        int2 se = staged[sbase + k];
        int rl = se.x >> 20;
        int pos = atomicAdd(&s_pos[rl], 1);
        cs[pos] = make_int2(se.x & 0xFFFFF, se.y);
    }
}

// ---------------- merged layer-1 SPMM (user + item rows in one grid) --------
// 8-way unroll: 8 independent gathers in flight per wave.
__global__ void csr_spmm2(const int* __restrict__ ptr_u, const int2* __restrict__ cs_u,
                          const int* __restrict__ ptr_i, const int2* __restrict__ cs_i,
                          const float* __restrict__ eu, const float* __restrict__ ei,
                          const float* __restrict__ d_i, const float* __restrict__ d_j,
                          float* __restrict__ g1u, float* __restrict__ g1i) {
    int w = (blockIdx.x * blockDim.x + threadIdx.x) >> 6;
    int lane = threadIdx.x & 63;
    const int* ptr; const int2* cs; const float* src; const float* self;
    const float* d; float* out; int row;
    if (w < USER_NUM) {
        row = w; ptr = ptr_u; cs = cs_u; src = ei; self = eu; d = d_i; out = g1u;
    } else if (w < USER_NUM + ITEM_NUM) {
        row = w - USER_NUM; ptr = ptr_i; cs = cs_i; src = eu; self = ei; d = d_j; out = g1i;
    } else return;
    int start = ptr[row], end = ptr[row + 1];
    float acc = self[(size_t)row * FACTOR + lane] * d[row];
    float a1 = 0.f;
    int k = start;
    for (; k + 8 <= end; k += 8) {
        int2 c0 = cs[k+0], c1 = cs[k+1], c2 = cs[k+2], c3 = cs[k+3];
        int2 c4 = cs[k+4], c5 = cs[k+5], c6 = cs[k+6], c7 = cs[k+7];
        float r0 = src[c0.x * FACTOR + lane];
        float r1 = src[c1.x * FACTOR + lane];
        float r2 = src[c2.x * FACTOR + lane];
        float r3 = src[c3.x * FACTOR + lane];
        float r4 = src[c4.x * FACTOR + lane];
        float r5 = src[c5.x * FACTOR + lane];
        float r6 = src[c6.x * FACTOR + lane];
        float r7 = src[c7.x * FACTOR + lane];
        acc = fmaf(__int_as_float(c0.y), r0, acc);
        a1  = fmaf(__int_as_float(c1.y), r1, a1);
        acc = fmaf(__int_as_float(c2.y), r2, acc);
        a1  = fmaf(__int_as_float(c3.y), r3, a1);
        acc = fmaf(__int_as_float(c4.y), r4, acc);
        a1  = fmaf(__int_as_float(c5.y), r5, a1);
        acc = fmaf(__int_as_float(c6.y), r6, acc);
        a1  = fmaf(__int_as_float(c7.y), r7, a1);
    }
    for (; k < end; ++k) {
        int2 c = cs[k];
        acc = fmaf(__int_as_float(c.y), src[c.x * FACTOR + lane], acc);
    }
    out[(size_t)row * FACTOR + lane] = acc + a1;
}

// ---------------- fused layer-2 + loss ----------------
__device__ __forceinline__ float gather_dot(const int2* __restrict__ cs, int start, int end,
                                            const float* __restrict__ tab, int lane) {
    float a0 = 0.f, a1 = 0.f, a2 = 0.f, a3 = 0.f;
    int k = start;
    for (; k + 4 <= end; k += 4) {
        int2 c0 = cs[k+0], c1 = cs[k+1], c2 = cs[k+2], c3 = cs[k+3];
        float r0 = tab[c0.x * FACTOR + lane];
        float r1 = tab[c1.x * FACTOR + lane];
        float r2 = tab[c2.x * FACTOR + lane];
        float r3 = tab[c3.x * FACTOR + lane];
        a0 = fmaf(__int_as_float(c0.y), r0, a0);
        a1 = fmaf(__int_as_float(c1.y), r1, a1);
        a2 = fmaf(__int_as_float(c2.y), r2, a2);
        a3 = fmaf(__int_as_float(c3.y), r3, a3);
    }
    for (; k < end; ++k) {
        int2 c = cs[k];
        a0 = fmaf(__int_as_float(c.y), tab[c.x * FACTOR + lane], a0);
    }
    return (a0 + a1) + (a2 + a3);
}

__global__ void fused_batch(const float* __restrict__ eu, const float* __restrict__ ei,
                            const float* __restrict__ g1u, const float* __restrict__ g1i,
                            const int* __restrict__ ptr_u, const int2* __restrict__ cs_u,
                            const int* __restrict__ ptr_i, const int2* __restrict__ cs_i,
                            const float* __restrict__ d_i, const float* __restrict__ d_j,
                            const int* __restrict__ user, const int* __restrict__ item_i,
                            const int* __restrict__ item_j, float* __restrict__ acc, int batch) {
    int w = (blockIdx.x * blockDim.x + threadIdx.x) >> 6;
    int lane = threadIdx.x & 63;
    if (w >= batch) return;
    int uu = user[w], ii = item_i[w], jj = item_j[w];

    size_t uo = (size_t)uu * FACTOR + lane;
    float g1 = g1u[uo];
    float U  = eu[uo] + g1 + g1 * d_i[uu] + gather_dot(cs_u, ptr_u[uu], ptr_u[uu + 1], g1i, lane);

    size_t io = (size_t)ii * FACTOR + lane;
    float h1 = g1i[io];
    float Pi = ei[io] + h1 + h1 * d_j[ii] + gather_dot(cs_i, ptr_i[ii], ptr_i[ii + 1], g1u, lane);

    size_t jo = (size_t)jj * FACTOR + lane;
    float h1j = g1i[jo];
    float Pj = ei[jo] + h1j + h1j * d_j[jj] + gather_dot(cs_i, ptr_i[jj], ptr_i[jj + 1], g1u, lane);

    float di  = U * Pi;
    float dj  = U * Pj;
    float su2 = U * U;
    float sp2 = Pi * Pi + Pj * Pj;
    for (int off = 32; off; off >>= 1) {
        di  += __shfl_down(di,  off, 64);
        dj  += __shfl_down(dj,  off, 64);
        su2 += __shfl_down(su2, off, 64);
        sp2 += __shfl_down(sp2, off, 64);
    }
    if (lane == 0) {
        float x  = -(di - dj);
        float sp = fmaxf(x, 0.f) + log1pf(expf(-fabsf(x)));
        atomicAdd(acc + 0, su2);
        atomicAdd(acc + 1, sp2);
        atomicAdd(acc + 2, sp);
    }
}

__global__ void finalize(const float* __restrict__ acc, float* __restrict__ out, int batch) {
    if (threadIdx.x == 0 && blockIdx.x == 0) {
        float inv_b  = 1.0f / (float)batch;
        float inv_bf = 1.0f / (float)(batch * FACTOR);
        out[0] = acc[2] * inv_b + LAMADA * acc[0] * inv_bf + LAMADA * acc[1] * inv_bf;
    }
}

// ---------------- fallback (atomic) path ----------------
__global__ void init_scale(const float* __restrict__ src, const float* __restrict__ d,
                           float* __restrict__ dst, int n_rows) {
    int gid = blockIdx.x * blockDim.x + threadIdx.x;
    int total = n_rows * 16;
    if (gid >= total) return;
    int r = gid >> 4;
    float s = d[r];
    float4 v = ((const float4*)src)[gid];
    v.x *= s; v.y *= s; v.z *= s; v.w *= s;
    ((float4*)dst)[gid] = v;
}

__global__ void edge_spmm(const float* __restrict__ srcU, const float* __restrict__ srcI,
                          float* __restrict__ dstU, float* __restrict__ dstI,
                          const int* __restrict__ u_idx, const int* __restrict__ i_idx,
                          const float* __restrict__ ui_vals, const float* __restrict__ iu_vals,
                          int n_edges) {
    long long gid = (long long)blockIdx.x * blockDim.x + threadIdx.x;
    int e = (int)(gid >> 4);
    if (e >= n_edges) return;
    int sub = ((int)gid & 15) * 4;
    int u = u_idx[e], i = i_idx[e];
    float uv = ui_vals[e], iv = iu_vals[e];
    size_t uo = (size_t)u * FACTOR + sub;
    size_t io = (size_t)i * FACTOR + sub;
    float4 a = *(const float4*)(srcI + io);
    float4 b = *(const float4*)(srcU + uo);
    float* du = dstU + uo;
    float* di = dstI + io;
    atomicAdd(du + 0, a.x * uv); atomicAdd(du + 1, a.y * uv);
    atomicAdd(du + 2, a.z * uv); atomicAdd(du + 3, a.w * uv);
    atomicAdd(di + 0, b.x * iv); atomicAdd(di + 1, b.y * iv);
    atomicAdd(di + 2, b.z * iv); atomicAdd(di + 3, b.w * iv);
}

__global__ void batch_loss(const float* __restrict__ eu, const float* __restrict__ ei,
                           const float* __restrict__ g1u, const float* __restrict__ g1i,
                           const float* __restrict__ g2u, const float* __restrict__ g2i,
                           const int* __restrict__ user, const int* __restrict__ item_i,
                           const int* __restrict__ item_j, float* __restrict__ acc, int batch) {
    int gid = blockIdx.x * blockDim.x + threadIdx.x;
    int w = gid >> 6;
    int lane = threadIdx.x & 63;
    if (w >= batch) return;
    int uu = user[w], ii = item_i[w], jj = item_j[w];
    size_t uo = (size_t)uu * FACTOR + lane;
    size_t io = (size_t)ii * FACTOR + lane;
    size_t jo = (size_t)jj * FACTOR + lane;
    float uvv = eu[uo] + g1u[uo] + g2u[uo];
    float piv = ei[io] + g1i[io] + g2i[io];
    float pjv = ei[jo] + g1i[jo] + g2i[jo];
    float di  = uvv * piv;
    float dj  = uvv * pjv;
    float su2 = uvv * uvv;
    float sp2 = piv * piv + pjv * pjv;
    for (int off = 32; off; off >>= 1) {
        di  += __shfl_down(di,  off, 64);
        dj  += __shfl_down(dj,  off, 64);
        su2 += __shfl_down(su2, off, 64);
        sp2 += __shfl_down(sp2, off, 64);
    }
    if (lane == 0) {
        float x  = -(di - dj);
        float sp = fmaxf(x, 0.f) + log1pf(expf(-fabsf(x)));
        atomicAdd(acc + 0, su2);
        atomicAdd(acc + 1, sp2);
        atomicAdd(acc + 2, sp);
    }
}

extern "C" void kernel_launch(void* const* d_in, const int* in_sizes, int n_in,
                              void* d_out, int out_size, void* d_ws, size_t ws_size,
                              hipStream_t stream) {
    const float* eu      = (const float*)d_in[0];
    const float* ei      = (const float*)d_in[1];
    const int*   u_idx   = (const int*)d_in[2];
    const int*   i_idx   = (const int*)d_in[3];
    const float* ui_vals = (const float*)d_in[4];
    const float* iu_vals = (const float*)d_in[5];
    const float* d_i     = (const float*)d_in[6];
    const float* d_j     = (const float*)d_in[7];
    const int*   user    = (const int*)d_in[8];
    const int*   item_i  = (const int*)d_in[9];
    const int*   item_j  = (const int*)d_in[10];
    int n_edges = in_sizes[2];
    int batch   = in_sizes[8];
    float* out  = (float*)d_out;

    const size_t FU = (size_t)USER_NUM * FACTOR;
    const size_t FI = (size_t)ITEM_NUM * FACTOR;
    const size_t NE = (size_t)n_edges;

    // Workspace layout. Overlays (exact-packed staging, NE entries each):
    //   staged_i -> region A (g1u/g1i, 38.4MB >= 25.6MB), dead before csr_spmm2 writes A
    //   staged_u -> region C (cs_i),   dead after bucket_finalize(u); finalize(i) then writes C
    // Order: place -> finalize_u (reads C, writes B) -> finalize_i (reads A, writes C) -> spmm (writes A)
    float* ws    = (float*)d_ws;
    float* g1u   = ws;                              // FU floats  (region A)
    float* g1i   = g1u + FU;                        // FI floats  (region A)
    int2*  cs_u  = (int2*)(g1i + FI);               // NE         (region B)
    int2*  cs_i  = cs_u + NE;                       // NE         (region C)
    int2*  staged_i = (int2*)ws;                    // NE  overlay A
    int2*  staged_u = cs_i;                         // NE  overlay C
    int*   ptr_u = (int*)(cs_i + NE);               // USER_NUM+1
    int*   ptr_i = ptr_u + (USER_NUM + 1);          // ITEM_NUM+1
    int*   cnt_u = ptr_i + (ITEM_NUM + 1);          // NBU
    int*   cnt_i = cnt_u + NBU;                     // NBI  (adjacent: one memset)
    int*   base_u = cnt_i + NBI;                    // NBU+1
    int*   base_i = base_u + (NBU + 1);             // NBI+1
    int*   cur_u  = base_i + (NBI + 1);             // NBU
    int*   cur_i  = cur_u + NBU;                    // NBI
    float* acc    = (float*)(cur_i + NBI);          // 4

    size_t need_bytes = ((size_t)(acc + 4) - (size_t)d_ws);

    if (ws_size >= need_bytes) {
        int nb1 = (n_edges + CHUNK - 1) / CHUNK;
        hipMemsetAsync(cnt_u, 0, (size_t)(NBU + NBI) * sizeof(int), stream);
        hipMemsetAsync(acc, 0, 4 * sizeof(float), stream);

        count_buckets<<<nb1, 256, 0, stream>>>(u_idx, i_idx, cnt_u, cnt_i, n_edges);
        bucket_scan<<<1, 512, 0, stream>>>(cnt_u, cnt_i, base_u, base_i, cur_u, cur_i,
                                           ptr_u + USER_NUM, ptr_i + ITEM_NUM, n_edges);
        place<<<nb1, 256, 0, stream>>>(u_idx, i_idx, ui_vals, iu_vals,
                                       cur_u, cur_i, staged_u, staged_i, n_edges);
        bucket_finalize<<<NBU, 256, 0, stream>>>(staged_u, base_u, ptr_u, cs_u, USER_NUM);
        bucket_finalize<<<NBI, 256, 0, stream>>>(staged_i, base_i, ptr_i, cs_i, ITEM_NUM);

        // merged layer-1 SPMM (user + item)
        int total_waves = USER_NUM + ITEM_NUM;
        csr_spmm2<<<(total_waves * 64 + 255) / 256, 256, 0, stream>>>(
            ptr_u, cs_u, ptr_i, cs_i, eu, ei, d_i, d_j, g1u, g1i);

        fused_batch<<<(batch * 64 + 255) / 256, 256, 0, stream>>>(eu, ei, g1u, g1i,
                                                                  ptr_u, cs_u, ptr_i, cs_i,
                                                                  d_i, d_j, user, item_i, item_j,
                                                                  acc, batch);
        finalize<<<1, 64, 0, stream>>>(acc, out, batch);
    } else {
        // fallback: atomic scatter path (77MB)
        float* f_g1u = ws;
        float* f_g1i = f_g1u + FU;
        float* f_g2u = f_g1i + FI;
        float* f_g2i = f_g2u + FU;
        float* f_acc = f_g2i + FI;
        hipMemsetAsync(f_acc, 0, 4 * sizeof(float), stream);
        long long tot = (long long)n_edges * 16;
        int eblocks = (int)((tot + 255) / 256);
        init_scale<<<(USER_NUM * 16 + 255) / 256, 256, 0, stream>>>(eu, d_i, f_g1u, USER_NUM);
        init_scale<<<(ITEM_NUM * 16 + 255) / 256, 256, 0, stream>>>(ei, d_j, f_g1i, ITEM_NUM);
        edge_spmm<<<eblocks, 256, 0, stream>>>(eu, ei, f_g1u, f_g1i, u_idx, i_idx, ui_vals, iu_vals, n_edges);
        init_scale<<<(USER_NUM * 16 + 255) / 256, 256, 0, stream>>>(f_g1u, d_i, f_g2u, USER_NUM);
        init_scale<<<(ITEM_NUM * 16 + 255) / 256, 256, 0, stream>>>(f_g1i, d_j, f_g2i, ITEM_NUM);
        edge_spmm<<<eblocks, 256, 0, stream>>>(f_g1u, f_g1i, f_g2u, f_g2i, u_idx, i_idx, ui_vals, iu_vals, n_edges);
        batch_loss<<<(batch * 64 + 255) / 256, 256, 0, stream>>>(eu, ei, f_g1u, f_g1i, f_g2u, f_g2i,
                                                                 user, item_i, item_j, f_acc, batch);
        finalize<<<1, 64, 0, stream>>>(f_acc, out, batch);
    }
}

// Round 7
// 772.712 us; speedup vs baseline: 14.2682x; 1.0002x over previous
//
#include <hip/hip_runtime.h>
#include <math.h>

#define USER_NUM 100000
#define ITEM_NUM 50000
#define FACTOR   64
#define LAMADA   0.0001f

#define NBU   391     // ceil(100000/256) buckets of 256 user rows
#define NBI   196     // ceil(50000/256)  buckets of 256 item rows
#define CHUNK 8192    // edges per partition block

// ---------------- build: per-block bucket count -> global counters ----------
__global__ void count_buckets(const int* __restrict__ u_idx, const int* __restrict__ i_idx,
                              int* __restrict__ cnt_u, int* __restrict__ cnt_i, int n_edges) {
    __shared__ int s_u[NBU];
    __shared__ int s_i[NBI];
    int tid = threadIdx.x;
    for (int b = tid; b < NBU; b += 256) s_u[b] = 0;
    for (int b = tid; b < NBI; b += 256) s_i[b] = 0;
    __syncthreads();
    int start = blockIdx.x * CHUNK, end = min(start + CHUNK, n_edges);
    for (int e = start + tid; e < end; e += 256) {
        atomicAdd(&s_u[u_idx[e] >> 8], 1);
        atomicAdd(&s_i[i_idx[e] >> 8], 1);
    }
    __syncthreads();
    for (int b = tid; b < NBU; b += 256) { int c = s_u[b]; if (c) atomicAdd(&cnt_u[b], c); }
    for (int b = tid; b < NBI; b += 256) { int c = s_i[b]; if (c) atomicAdd(&cnt_i[b], c); }
}

// ---------------- build: scan bucket totals -> exact bases + cursors --------
__global__ void bucket_scan(const int* __restrict__ cnt_u, const int* __restrict__ cnt_i,
                            int* __restrict__ base_u, int* __restrict__ base_i,
                            int* __restrict__ cur_u, int* __restrict__ cur_i,
                            int* __restrict__ ptr_u_end, int* __restrict__ ptr_i_end,
                            float* __restrict__ acc, int n_edges) {
    __shared__ int s[512];
    int tid = threadIdx.x;
    if (tid < 4) acc[tid] = 0.f;
    int x = (tid < NBU) ? cnt_u[tid] : 0;
    s[tid] = x; __syncthreads();
    for (int off = 1; off < 512; off <<= 1) {
        int t = (tid >= off) ? s[tid - off] : 0;
        __syncthreads(); s[tid] += t; __syncthreads();
    }
    if (tid < NBU) { int b = s[tid] - x; base_u[tid] = b; cur_u[tid] = b; }
    if (tid == 511) { base_u[NBU] = s[511]; *ptr_u_end = n_edges; }
    __syncthreads();
    int y = (tid < NBI) ? cnt_i[tid] : 0;
    s[tid] = y; __syncthreads();
    for (int off = 1; off < 512; off <<= 1) {
        int t = (tid >= off) ? s[tid - off] : 0;
        __syncthreads(); s[tid] += t; __syncthreads();
    }
    if (tid < NBI) { int b = s[tid] - y; base_i[tid] = b; cur_i[tid] = b; }
    if (tid == 511) { base_i[NBI] = s[511]; *ptr_i_end = n_edges; }
}

// ---------------- build: place packed (rowlocal<<20|col, val) into staging --
__global__ void place(const int* __restrict__ u_idx, const int* __restrict__ i_idx,
                      const float* __restrict__ ui_vals, const float* __restrict__ iu_vals,
                      int* __restrict__ cur_u, int* __restrict__ cur_i,
                      int2* __restrict__ staged_u, int2* __restrict__ staged_i, int n_edges) {
    __shared__ int s_u[NBU];
    __shared__ int s_i[NBI];
    int tid = threadIdx.x;
    for (int b = tid; b < NBU; b += 256) s_u[b] = 0;
    for (int b = tid; b < NBI; b += 256) s_i[b] = 0;
    __syncthreads();
    int start = blockIdx.x * CHUNK, end = min(start + CHUNK, n_edges);
    for (int e = start + tid; e < end; e += 256) {
        atomicAdd(&s_u[u_idx[e] >> 8], 1);
        atomicAdd(&s_i[i_idx[e] >> 8], 1);
    }
    __syncthreads();
    for (int b = tid; b < NBU; b += 256) { int c = s_u[b]; s_u[b] = c ? atomicAdd(&cur_u[b], c) : 0; }
    for (int b = tid; b < NBI; b += 256) { int c = s_i[b]; s_i[b] = c ? atomicAdd(&cur_i[b], c) : 0; }
    __syncthreads();
    for (int e = start + tid; e < end; e += 256) {
        int u = u_idx[e], i = i_idx[e];
        int pu = atomicAdd(&s_u[u >> 8], 1);
        staged_u[pu] = make_int2(((u & 255) << 20) | i, __float_as_int(ui_vals[e]));
        int pi = atomicAdd(&s_i[i >> 8], 1);
        staged_i[pi] = make_int2(((i & 255) << 20) | u, __float_as_int(iu_vals[e]));
    }
}

// ---------------- build: per-bucket finalize, col-tile-sorted CSR -----------
// LDS counting sort keyed by (row_local, col>>13): within each row, edges come
// out ordered by 2MB source-table tile -> cross-wave L2 locality in the SPMM.
__global__ void bucket_finalize_sorted(const int2* __restrict__ staged, const int* __restrict__ base,
                                       int* __restrict__ ptr, int2* __restrict__ cs, int n_rows,
                                       int tile_bits) {
    __shared__ int s[4096];
    __shared__ int s2[256];
    int b = blockIdx.x, tid = threadIdx.x;
    int nt = 1 << tile_bits;
    int nbins = 256 << tile_bits;
    for (int k = tid; k < nbins; k += 256) s[k] = 0;
    __syncthreads();
    int sbase = base[b], nE = base[b + 1] - sbase;
    for (int k = tid; k < nE; k += 256) {
        int x = staged[sbase + k].x;
        atomicAdd(&s[((x >> 20) << tile_bits) | ((x & 0xFFFFF) >> 13)], 1);
    }
    __syncthreads();
    // thread tid owns row tid: local prefix over its tiles
    int rowbase = tid << tile_bits;
    int loc[16];
    int run = 0;
    #pragma unroll
    for (int t = 0; t < 16; ++t) {
        if (t < nt) { loc[t] = run; run += s[rowbase + t]; }
    }
    // block exclusive scan of row totals
    s2[tid] = run; __syncthreads();
    int x = run;
    for (int off = 1; off < 256; off <<= 1) {
        int t = (tid >= off) ? s2[tid - off] : 0;
        __syncthreads(); s2[tid] += t; __syncthreads();
    }
    int row_excl = s2[tid] - x + sbase;
    int r = (b << 8) + tid;
    if (r < n_rows) ptr[r] = row_excl;
    #pragma unroll
    for (int t = 0; t < 16; ++t) {
        if (t < nt) s[rowbase + t] = row_excl + loc[t];
    }
    __syncthreads();
    for (int k = tid; k < nE; k += 256) {
        int2 se = staged[sbase + k];
        int rl = se.x >> 20, col = se.x & 0xFFFFF;
        int pos = atomicAdd(&s[(rl << tile_bits) | (col >> 13)], 1);
        cs[pos] = make_int2(col, se.y);
    }
}

// ---------------- merged layer-1 SPMM (user + item rows in one grid) --------
__global__ void csr_spmm2(const int* __restrict__ ptr_u, const int2* __restrict__ cs_u,
                          const int* __restrict__ ptr_i, const int2* __restrict__ cs_i,
                          const float* __restrict__ eu, const float* __restrict__ ei,
                          const float* __restrict__ d_i, const float* __restrict__ d_j,
                          float* __restrict__ g1u, float* __restrict__ g1i) {
    int w = (blockIdx.x * blockDim.x + threadIdx.x) >> 6;
    int lane = threadIdx.x & 63;
    const int* ptr; const int2* cs; const float* src; const float* self;
    const float* d; float* out; int row;
    if (w < USER_NUM) {
        row = w; ptr = ptr_u; cs = cs_u; src = ei; self = eu; d = d_i; out = g1u;
    } else if (w < USER_NUM + ITEM_NUM) {
        row = w - USER_NUM; ptr = ptr_i; cs = cs_i; src = eu; self = ei; d = d_j; out = g1i;
    } else return;
    int start = ptr[row], end = ptr[row + 1];
    float acc = self[(size_t)row * FACTOR + lane] * d[row];
    float a1 = 0.f;
    int k = start;
    for (; k + 8 <= end; k += 8) {
        int2 c0 = cs[k+0], c1 = cs[k+1], c2 = cs[k+2], c3 = cs[k+3];
        int2 c4 = cs[k+4], c5 = cs[k+5], c6 = cs[k+6], c7 = cs[k+7];
        float r0 = src[c0.x * FACTOR + lane];
        float r1 = src[c1.x * FACTOR + lane];
        float r2 = src[c2.x * FACTOR + lane];
        float r3 = src[c3.x * FACTOR + lane];
        float r4 = src[c4.x * FACTOR + lane];
        float r5 = src[c5.x * FACTOR + lane];
        float r6 = src[c6.x * FACTOR + lane];
        float r7 = src[c7.x * FACTOR + lane];
        acc = fmaf(__int_as_float(c0.y), r0, acc);
        a1  = fmaf(__int_as_float(c1.y), r1, a1);
        acc = fmaf(__int_as_float(c2.y), r2, acc);
        a1  = fmaf(__int_as_float(c3.y), r3, a1);
        acc = fmaf(__int_as_float(c4.y), r4, acc);
        a1  = fmaf(__int_as_float(c5.y), r5, a1);
        acc = fmaf(__int_as_float(c6.y), r6, acc);
        a1  = fmaf(__int_as_float(c7.y), r7, a1);
    }
    for (; k < end; ++k) {
        int2 c = cs[k];
        acc = fmaf(__int_as_float(c.y), src[c.x * FACTOR + lane], acc);
    }
    out[(size_t)row * FACTOR + lane] = acc + a1;
}

// ---------------- fused layer-2 + loss ----------------
__device__ __forceinline__ float gather_dot(const int2* __restrict__ cs, int start, int end,
                                            const float* __restrict__ tab, int lane) {
    float a0 = 0.f, a1 = 0.f, a2 = 0.f, a3 = 0.f;
    int k = start;
    for (; k + 4 <= end; k += 4) {
        int2 c0 = cs[k+0], c1 = cs[k+1], c2 = cs[k+2], c3 = cs[k+3];
        float r0 = tab[c0.x * FACTOR + lane];
        float r1 = tab[c1.x * FACTOR + lane];
        float r2 = tab[c2.x * FACTOR + lane];
        float r3 = tab[c3.x * FACTOR + lane];
        a0 = fmaf(__int_as_float(c0.y), r0, a0);
        a1 = fmaf(__int_as_float(c1.y), r1, a1);
        a2 = fmaf(__int_as_float(c2.y), r2, a2);
        a3 = fmaf(__int_as_float(c3.y), r3, a3);
    }
    for (; k < end; ++k) {
        int2 c = cs[k];
        a0 = fmaf(__int_as_float(c.y), tab[c.x * FACTOR + lane], a0);
    }
    return (a0 + a1) + (a2 + a3);
}

__global__ void fused_batch(const float* __restrict__ eu, const float* __restrict__ ei,
                            const float* __restrict__ g1u, const float* __restrict__ g1i,
                            const int* __restrict__ ptr_u, const int2* __restrict__ cs_u,
                            const int* __restrict__ ptr_i, const int2* __restrict__ cs_i,
                            const float* __restrict__ d_i, const float* __restrict__ d_j,
                            const int* __restrict__ user, const int* __restrict__ item_i,
                            const int* __restrict__ item_j, float* __restrict__ acc, int batch) {
    int w = (blockIdx.x * blockDim.x + threadIdx.x) >> 6;
    int lane = threadIdx.x & 63;
    if (w >= batch) return;
    int uu = user[w], ii = item_i[w], jj = item_j[w];

    size_t uo = (size_t)uu * FACTOR + lane;
    float g1 = g1u[uo];
    float U  = eu[uo] + g1 + g1 * d_i[uu] + gather_dot(cs_u, ptr_u[uu], ptr_u[uu + 1], g1i, lane);

    size_t io = (size_t)ii * FACTOR + lane;
    float h1 = g1i[io];
    float Pi = ei[io] + h1 + h1 * d_j[ii] + gather_dot(cs_i, ptr_i[ii], ptr_i[ii + 1], g1u, lane);

    size_t jo = (size_t)jj * FACTOR + lane;
    float h1j = g1i[jo];
    float Pj = ei[jo] + h1j + h1j * d_j[jj] + gather_dot(cs_i, ptr_i[jj], ptr_i[jj + 1], g1u, lane);

    float di  = U * Pi;
    float dj  = U * Pj;
    float su2 = U * U;
    float sp2 = Pi * Pi + Pj * Pj;
    for (int off = 32; off; off >>= 1) {
        di  += __shfl_down(di,  off, 64);
        dj  += __shfl_down(dj,  off, 64);
        su2 += __shfl_down(su2, off, 64);
        sp2 += __shfl_down(sp2, off, 64);
    }
    if (lane == 0) {
        float x  = -(di - dj);
        float sp = fmaxf(x, 0.f) + log1pf(expf(-fabsf(x)));
        atomicAdd(acc + 0, su2);
        atomicAdd(acc + 1, sp2);
        atomicAdd(acc + 2, sp);
    }
}

__global__ void finalize(const float* __restrict__ acc, float* __restrict__ out, int batch) {
    if (threadIdx.x == 0 && blockIdx.x == 0) {
        float inv_b  = 1.0f / (float)batch;
        float inv_bf = 1.0f / (float)(batch * FACTOR);
        out[0] = acc[2] * inv_b + LAMADA * acc[0] * inv_bf + LAMADA * acc[1] * inv_bf;
    }
}

// ---------------- fallback (atomic) path ----------------
__global__ void init_scale(const float* __restrict__ src, const float* __restrict__ d,
                           float* __restrict__ dst, int n_rows) {
    int gid = blockIdx.x * blockDim.x + threadIdx.x;
    int total = n_rows * 16;
    if (gid >= total) return;
    int r = gid >> 4;
    float s = d[r];
    float4 v = ((const float4*)src)[gid];
    v.x *= s; v.y *= s; v.z *= s; v.w *= s;
    ((float4*)dst)[gid] = v;
}

__global__ void edge_spmm(const float* __restrict__ srcU, const float* __restrict__ srcI,
                          float* __restrict__ dstU, float* __restrict__ dstI,
                          const int* __restrict__ u_idx, const int* __restrict__ i_idx,
                          const float* __restrict__ ui_vals, const float* __restrict__ iu_vals,
                          int n_edges) {
    long long gid = (long long)blockIdx.x * blockDim.x + threadIdx.x;
    int e = (int)(gid >> 4);
    if (e >= n_edges) return;
    int sub = ((int)gid & 15) * 4;
    int u = u_idx[e], i = i_idx[e];
    float uv = ui_vals[e], iv = iu_vals[e];
    size_t uo = (size_t)u * FACTOR + sub;
    size_t io = (size_t)i * FACTOR + sub;
    float4 a = *(const float4*)(srcI + io);
    float4 b = *(const float4*)(srcU + uo);
    float* du = dstU + uo;
    float* di = dstI + io;
    atomicAdd(du + 0, a.x * uv); atomicAdd(du + 1, a.y * uv);
    atomicAdd(du + 2, a.z * uv); atomicAdd(du + 3, a.w * uv);
    atomicAdd(di + 0, b.x * iv); atomicAdd(di + 1, b.y * iv);
    atomicAdd(di + 2, b.z * iv); atomicAdd(di + 3, b.w * iv);
}

__global__ void batch_loss(const float* __restrict__ eu, const float* __restrict__ ei,
                           const float* __restrict__ g1u, const float* __restrict__ g1i,
                           const float* __restrict__ g2u, const float* __restrict__ g2i,
                           const int* __restrict__ user, const int* __restrict__ item_i,
                           const int* __restrict__ item_j, float* __restrict__ acc, int batch) {
    int gid = blockIdx.x * blockDim.x + threadIdx.x;
    int w = gid >> 6;
    int lane = threadIdx.x & 63;
    if (w >= batch) return;
    int uu = user[w], ii = item_i[w], jj = item_j[w];
    size_t uo = (size_t)uu * FACTOR + lane;
    size_t io = (size_t)ii * FACTOR + lane;
    size_t jo = (size_t)jj * FACTOR + lane;
    float uvv = eu[uo] + g1u[uo] + g2u[uo];
    float piv = ei[io] + g1i[io] + g2i[io];
    float pjv = ei[jo] + g1i[jo] + g2i[jo];
    float di  = uvv * piv;
    float dj  = uvv * pjv;
    float su2 = uvv * uvv;
    float sp2 = piv * piv + pjv * pjv;
    for (int off = 32; off; off >>= 1) {
        di  += __shfl_down(di,  off, 64);
        dj  += __shfl_down(dj,  off, 64);
        su2 += __shfl_down(su2, off, 64);
        sp2 += __shfl_down(sp2, off, 64);
    }
    if (lane == 0) {
        float x  = -(di - dj);
        float sp = fmaxf(x, 0.f) + log1pf(expf(-fabsf(x)));
        atomicAdd(acc + 0, su2);
        atomicAdd(acc + 1, sp2);
        atomicAdd(acc + 2, sp);
    }
}

extern "C" void kernel_launch(void* const* d_in, const int* in_sizes, int n_in,
                              void* d_out, int out_size, void* d_ws, size_t ws_size,
                              hipStream_t stream) {
    const float* eu      = (const float*)d_in[0];
    const float* ei      = (const float*)d_in[1];
    const int*   u_idx   = (const int*)d_in[2];
    const int*   i_idx   = (const int*)d_in[3];
    const float* ui_vals = (const float*)d_in[4];
    const float* iu_vals = (const float*)d_in[5];
    const float* d_i     = (const float*)d_in[6];
    const float* d_j     = (const float*)d_in[7];
    const int*   user    = (const int*)d_in[8];
    const int*   item_i  = (const int*)d_in[9];
    const int*   item_j  = (const int*)d_in[10];
    int n_edges = in_sizes[2];
    int batch   = in_sizes[8];
    float* out  = (float*)d_out;

    const size_t FU = (size_t)USER_NUM * FACTOR;
    const size_t FI = (size_t)ITEM_NUM * FACTOR;
    const size_t NE = (size_t)n_edges;

    // Workspace layout. Overlays (exact-packed staging, NE entries each):
    //   staged_i -> region A (g1u/g1i), dead before csr_spmm2 writes A
    //   staged_u -> region C (cs_i),    dead after finalize(u); finalize(i) then writes C
    // Order: place -> finalize_u (reads C, writes B) -> finalize_i (reads A, writes C) -> spmm (writes A)
    float* ws    = (float*)d_ws;
    float* g1u   = ws;                              // FU floats  (region A)
    float* g1i   = g1u + FU;                        // FI floats  (region A)
    int2*  cs_u  = (int2*)(g1i + FI);               // NE         (region B)
    int2*  cs_i  = cs_u + NE;                       // NE         (region C)
    int2*  staged_i = (int2*)ws;                    // NE  overlay A
    int2*  staged_u = cs_i;                         // NE  overlay C
    int*   ptr_u = (int*)(cs_i + NE);               // USER_NUM+1
    int*   ptr_i = ptr_u + (USER_NUM + 1);          // ITEM_NUM+1
    int*   cnt_u = ptr_i + (ITEM_NUM + 1);          // NBU
    int*   cnt_i = cnt_u + NBU;                     // NBI  (adjacent: one memset)
    int*   base_u = cnt_i + NBI;                    // NBU+1
    int*   base_i = base_u + (NBU + 1);             // NBI+1
    int*   cur_u  = base_i + (NBI + 1);             // NBU
    int*   cur_i  = cur_u + NBU;                    // NBI
    float* acc    = (float*)(cur_i + NBI);          // 4

    size_t need_bytes = ((size_t)(acc + 4) - (size_t)d_ws);

    if (ws_size >= need_bytes) {
        int nb1 = (n_edges + CHUNK - 1) / CHUNK;
        hipMemsetAsync(cnt_u, 0, (size_t)(NBU + NBI) * sizeof(int), stream);

        count_buckets<<<nb1, 256, 0, stream>>>(u_idx, i_idx, cnt_u, cnt_i, n_edges);
        bucket_scan<<<1, 512, 0, stream>>>(cnt_u, cnt_i, base_u, base_i, cur_u, cur_i,
                                           ptr_u + USER_NUM, ptr_i + ITEM_NUM, acc, n_edges);
        place<<<nb1, 256, 0, stream>>>(u_idx, i_idx, ui_vals, iu_vals,
                                       cur_u, cur_i, staged_u, staged_i, n_edges);
        // user-side: cols are items (<50000) -> 7 tiles -> 3 tile bits
        bucket_finalize_sorted<<<NBU, 256, 0, stream>>>(staged_u, base_u, ptr_u, cs_u, USER_NUM, 3);
        // item-side: cols are users (<100000) -> 13 tiles -> 4 tile bits
        bucket_finalize_sorted<<<NBI, 256, 0, stream>>>(staged_i, base_i, ptr_i, cs_i, ITEM_NUM, 4);

        // merged layer-1 SPMM (user + item)
        int total_waves = USER_NUM + ITEM_NUM;
        csr_spmm2<<<(total_waves * 64 + 255) / 256, 256, 0, stream>>>(
            ptr_u, cs_u, ptr_i, cs_i, eu, ei, d_i, d_j, g1u, g1i);

        fused_batch<<<(batch * 64 + 255) / 256, 256, 0, stream>>>(eu, ei, g1u, g1i,
                                                                  ptr_u, cs_u, ptr_i, cs_i,
                                                                  d_i, d_j, user, item_i, item_j,
                                                                  acc, batch);
        finalize<<<1, 64, 0, stream>>>(acc, out, batch);
    } else {
        // fallback: atomic scatter path (77MB)
        float* f_g1u = ws;
        float* f_g1i = f_g1u + FU;
        float* f_g2u = f_g1i + FI;
        float* f_g2i = f_g2u + FU;
        float* f_acc = f_g2i + FI;
        hipMemsetAsync(f_acc, 0, 4 * sizeof(float), stream);
        long long tot = (long long)n_edges * 16;
        int eblocks = (int)((tot + 255) / 256);
        init_scale<<<(USER_NUM * 16 + 255) / 256, 256, 0, stream>>>(eu, d_i, f_g1u, USER_NUM);
        init_scale<<<(ITEM_NUM * 16 + 255) / 256, 256, 0, stream>>>(ei, d_j, f_g1i, ITEM_NUM);
        edge_spmm<<<eblocks, 256, 0, stream>>>(eu, ei, f_g1u, f_g1i, u_idx, i_idx, ui_vals, iu_vals, n_edges);
        init_scale<<<(USER_NUM * 16 + 255) / 256, 256, 0, stream>>>(f_g1u, d_i, f_g2u, USER_NUM);
        init_scale<<<(ITEM_NUM * 16 + 255) / 256, 256, 0, stream>>>(f_g1i, d_j, f_g2i, ITEM_NUM);
        edge_spmm<<<eblocks, 256, 0, stream>>>(f_g1u, f_g1i, f_g2u, f_g2i, u_idx, i_idx, ui_vals, iu_vals, n_edges);
        batch_loss<<<(batch * 64 + 255) / 256, 256, 0, stream>>>(eu, ei, f_g1u, f_g1i, f_g2u, f_g2i,
                                                                 user, item_i, item_j, f_acc, batch);
        finalize<<<1, 64, 0, stream>>>(f_acc, out, batch);
    }
}

// Round 8
// 735.595 us; speedup vs baseline: 14.9881x; 1.0505x over previous
//
#include <hip/hip_runtime.h>
#include <math.h>

#define USER_NUM 100000
#define ITEM_NUM 50000
#define FACTOR   64
#define LAMADA   0.0001f

#define NBU   391     // ceil(100000/256) buckets of 256 user rows
#define NBI   196     // ceil(50000/256)  buckets of 256 item rows
#define CHUNK 8192    // edges per partition block

typedef unsigned short ushort_t;
typedef unsigned int   uint_t;

__device__ __forceinline__ ushort_t f2bf(float f) {
    uint_t u = __float_as_uint(f);
    u += 0x7FFFu + ((u >> 16) & 1u);        // round-to-nearest-even
    return (ushort_t)(u >> 16);
}
__device__ __forceinline__ float bf2f(ushort_t h) {
    return __uint_as_float((uint_t)h << 16);
}

// ---------------- fp32 -> bf16 table convert (4 floats/thread) --------------
__global__ void to_bf16(const float* __restrict__ src, ushort_t* __restrict__ dst, int n4) {
    int gid = blockIdx.x * blockDim.x + threadIdx.x;
    if (gid >= n4) return;
    float4 v = ((const float4*)src)[gid];
    ushort4 o;
    o.x = f2bf(v.x); o.y = f2bf(v.y); o.z = f2bf(v.z); o.w = f2bf(v.w);
    ((ushort4*)dst)[gid] = o;
}

// ---------------- build: per-block bucket count -> global counters ----------
__global__ void count_buckets(const int* __restrict__ u_idx, const int* __restrict__ i_idx,
                              int* __restrict__ cnt_u, int* __restrict__ cnt_i, int n_edges) {
    __shared__ int s_u[NBU];
    __shared__ int s_i[NBI];
    int tid = threadIdx.x;
    for (int b = tid; b < NBU; b += 256) s_u[b] = 0;
    for (int b = tid; b < NBI; b += 256) s_i[b] = 0;
    __syncthreads();
    int start = blockIdx.x * CHUNK, end = min(start + CHUNK, n_edges);
    for (int e = start + tid; e < end; e += 256) {
        atomicAdd(&s_u[u_idx[e] >> 8], 1);
        atomicAdd(&s_i[i_idx[e] >> 8], 1);
    }
    __syncthreads();
    for (int b = tid; b < NBU; b += 256) { int c = s_u[b]; if (c) atomicAdd(&cnt_u[b], c); }
    for (int b = tid; b < NBI; b += 256) { int c = s_i[b]; if (c) atomicAdd(&cnt_i[b], c); }
}

// ---------------- build: scan bucket totals -> exact bases + cursors --------
__global__ void bucket_scan(const int* __restrict__ cnt_u, const int* __restrict__ cnt_i,
                            int* __restrict__ base_u, int* __restrict__ base_i,
                            int* __restrict__ cur_u, int* __restrict__ cur_i,
                            int* __restrict__ ptr_u_end, int* __restrict__ ptr_i_end,
                            float* __restrict__ acc, int n_edges) {
    __shared__ int s[512];
    int tid = threadIdx.x;
    if (tid < 4) acc[tid] = 0.f;
    int x = (tid < NBU) ? cnt_u[tid] : 0;
    s[tid] = x; __syncthreads();
    for (int off = 1; off < 512; off <<= 1) {
        int t = (tid >= off) ? s[tid - off] : 0;
        __syncthreads(); s[tid] += t; __syncthreads();
    }
    if (tid < NBU) { int b = s[tid] - x; base_u[tid] = b; cur_u[tid] = b; }
    if (tid == 511) { base_u[NBU] = s[511]; *ptr_u_end = n_edges; }
    __syncthreads();
    int y = (tid < NBI) ? cnt_i[tid] : 0;
    s[tid] = y; __syncthreads();
    for (int off = 1; off < 512; off <<= 1) {
        int t = (tid >= off) ? s[tid - off] : 0;
        __syncthreads(); s[tid] += t; __syncthreads();
    }
    if (tid < NBI) { int b = s[tid] - y; base_i[tid] = b; cur_i[tid] = b; }
    if (tid == 511) { base_i[NBI] = s[511]; *ptr_i_end = n_edges; }
}

// ---------------- build: place packed (rowlocal<<20|col, val) into staging --
__global__ void place(const int* __restrict__ u_idx, const int* __restrict__ i_idx,
                      const float* __restrict__ ui_vals, const float* __restrict__ iu_vals,
                      int* __restrict__ cur_u, int* __restrict__ cur_i,
                      int2* __restrict__ staged_u, int2* __restrict__ staged_i, int n_edges) {
    __shared__ int s_u[NBU];
    __shared__ int s_i[NBI];
    int tid = threadIdx.x;
    for (int b = tid; b < NBU; b += 256) s_u[b] = 0;
    for (int b = tid; b < NBI; b += 256) s_i[b] = 0;
    __syncthreads();
    int start = blockIdx.x * CHUNK, end = min(start + CHUNK, n_edges);
    for (int e = start + tid; e < end; e += 256) {
        atomicAdd(&s_u[u_idx[e] >> 8], 1);
        atomicAdd(&s_i[i_idx[e] >> 8], 1);
    }
    __syncthreads();
    for (int b = tid; b < NBU; b += 256) { int c = s_u[b]; s_u[b] = c ? atomicAdd(&cur_u[b], c) : 0; }
    for (int b = tid; b < NBI; b += 256) { int c = s_i[b]; s_i[b] = c ? atomicAdd(&cur_i[b], c) : 0; }
    __syncthreads();
    for (int e = start + tid; e < end; e += 256) {
        int u = u_idx[e], i = i_idx[e];
        int pu = atomicAdd(&s_u[u >> 8], 1);
        staged_u[pu] = make_int2(((u & 255) << 20) | i, __float_as_int(ui_vals[e]));
        int pi = atomicAdd(&s_i[i >> 8], 1);
        staged_i[pi] = make_int2(((i & 255) << 20) | u, __float_as_int(iu_vals[e]));
    }
}

// ---------------- build: per-bucket finalize (ptr + CSR), streams staging ---
__global__ void bucket_finalize(const int2* __restrict__ staged, const int* __restrict__ base,
                                int* __restrict__ ptr, int2* __restrict__ cs, int n_rows) {
    __shared__ int s_cnt[256];
    __shared__ int s_pos[256];
    int b = blockIdx.x, tid = threadIdx.x;
    int sbase = base[b], nE = base[b + 1] - sbase;
    s_cnt[tid] = 0;
    __syncthreads();
    for (int k = tid; k < nE; k += 256) atomicAdd(&s_cnt[staged[sbase + k].x >> 20], 1);
    __syncthreads();
    int x = s_cnt[tid];
    s_pos[tid] = x; __syncthreads();
    for (int off = 1; off < 256; off <<= 1) {
        int t = (tid >= off) ? s_pos[tid - off] : 0;
        __syncthreads(); s_pos[tid] += t; __syncthreads();
    }
    int excl = s_pos[tid] - x + sbase;
    int r = (b << 8) + tid;
    if (r < n_rows) ptr[r] = excl;
    s_pos[tid] = excl;
    __syncthreads();
    for (int k = tid; k < nE; k += 256) {
        int2 se = staged[sbase + k];
        int rl = se.x >> 20;
        int pos = atomicAdd(&s_pos[rl], 1);
        cs[pos] = make_int2(se.x & 0xFFFFF, se.y);
    }
}

// ---------------- merged layer-1 SPMM, bf16 gathers, fp32 accumulate --------
__global__ void csr_spmm2(const int* __restrict__ ptr_u, const int2* __restrict__ cs_u,
                          const int* __restrict__ ptr_i, const int2* __restrict__ cs_i,
                          const ushort_t* __restrict__ beu, const ushort_t* __restrict__ bei,
                          const float* __restrict__ eu, const float* __restrict__ ei,
                          const float* __restrict__ d_i, const float* __restrict__ d_j,
                          ushort_t* __restrict__ g1u, ushort_t* __restrict__ g1i) {
    int w = (blockIdx.x * blockDim.x + threadIdx.x) >> 6;
    int lane = threadIdx.x & 63;
    const int* ptr; const int2* cs; const ushort_t* src; const float* self;
    const float* d; ushort_t* out; int row;
    if (w < USER_NUM) {
        row = w; ptr = ptr_u; cs = cs_u; src = bei; self = eu; d = d_i; out = g1u;
    } else if (w < USER_NUM + ITEM_NUM) {
        row = w - USER_NUM; ptr = ptr_i; cs = cs_i; src = beu; self = ei; d = d_j; out = g1i;
    } else return;
    int start = ptr[row], end = ptr[row + 1];
    float acc = self[(size_t)row * FACTOR + lane] * d[row];
    float a1 = 0.f;
    int k = start;
    for (; k + 8 <= end; k += 8) {
        int2 c0 = cs[k+0], c1 = cs[k+1], c2 = cs[k+2], c3 = cs[k+3];
        int2 c4 = cs[k+4], c5 = cs[k+5], c6 = cs[k+6], c7 = cs[k+7];
        ushort_t r0 = src[c0.x * FACTOR + lane];
        ushort_t r1 = src[c1.x * FACTOR + lane];
        ushort_t r2 = src[c2.x * FACTOR + lane];
        ushort_t r3 = src[c3.x * FACTOR + lane];
        ushort_t r4 = src[c4.x * FACTOR + lane];
        ushort_t r5 = src[c5.x * FACTOR + lane];
        ushort_t r6 = src[c6.x * FACTOR + lane];
        ushort_t r7 = src[c7.x * FACTOR + lane];
        acc = fmaf(__int_as_float(c0.y), bf2f(r0), acc);
        a1  = fmaf(__int_as_float(c1.y), bf2f(r1), a1);
        acc = fmaf(__int_as_float(c2.y), bf2f(r2), acc);
        a1  = fmaf(__int_as_float(c3.y), bf2f(r3), a1);
        acc = fmaf(__int_as_float(c4.y), bf2f(r4), acc);
        a1  = fmaf(__int_as_float(c5.y), bf2f(r5), a1);
        acc = fmaf(__int_as_float(c6.y), bf2f(r6), acc);
        a1  = fmaf(__int_as_float(c7.y), bf2f(r7), a1);
    }
    for (; k < end; ++k) {
        int2 c = cs[k];
        acc = fmaf(__int_as_float(c.y), bf2f(src[c.x * FACTOR + lane]), acc);
    }
    out[(size_t)row * FACTOR + lane] = f2bf(acc + a1);
}

// ---------------- fused layer-2 + loss (bf16 gathers) ----------------
__device__ __forceinline__ float gather_dot(const int2* __restrict__ cs, int start, int end,
                                            const ushort_t* __restrict__ tab, int lane) {
    float a0 = 0.f, a1 = 0.f, a2 = 0.f, a3 = 0.f;
    int k = start;
    for (; k + 8 <= end; k += 8) {
        int2 c0 = cs[k+0], c1 = cs[k+1], c2 = cs[k+2], c3 = cs[k+3];
        int2 c4 = cs[k+4], c5 = cs[k+5], c6 = cs[k+6], c7 = cs[k+7];
        ushort_t r0 = tab[c0.x * FACTOR + lane];
        ushort_t r1 = tab[c1.x * FACTOR + lane];
        ushort_t r2 = tab[c2.x * FACTOR + lane];
        ushort_t r3 = tab[c3.x * FACTOR + lane];
        ushort_t r4 = tab[c4.x * FACTOR + lane];
        ushort_t r5 = tab[c5.x * FACTOR + lane];
        ushort_t r6 = tab[c6.x * FACTOR + lane];
        ushort_t r7 = tab[c7.x * FACTOR + lane];
        a0 = fmaf(__int_as_float(c0.y), bf2f(r0), a0);
        a1 = fmaf(__int_as_float(c1.y), bf2f(r1), a1);
        a2 = fmaf(__int_as_float(c2.y), bf2f(r2), a2);
        a3 = fmaf(__int_as_float(c3.y), bf2f(r3), a3);
        a0 = fmaf(__int_as_float(c4.y), bf2f(r4), a0);
        a1 = fmaf(__int_as_float(c5.y), bf2f(r5), a1);
        a2 = fmaf(__int_as_float(c6.y), bf2f(r6), a2);
        a3 = fmaf(__int_as_float(c7.y), bf2f(r7), a3);
    }
    for (; k < end; ++k) {
        int2 c = cs[k];
        a0 = fmaf(__int_as_float(c.y), bf2f(tab[c.x * FACTOR + lane]), a0);
    }
    return (a0 + a1) + (a2 + a3);
}

__global__ void fused_batch(const float* __restrict__ eu, const float* __restrict__ ei,
                            const ushort_t* __restrict__ g1u, const ushort_t* __restrict__ g1i,
                            const int* __restrict__ ptr_u, const int2* __restrict__ cs_u,
                            const int* __restrict__ ptr_i, const int2* __restrict__ cs_i,
                            const float* __restrict__ d_i, const float* __restrict__ d_j,
                            const int* __restrict__ user, const int* __restrict__ item_i,
                            const int* __restrict__ item_j, float* __restrict__ acc, int batch) {
    int w = (blockIdx.x * blockDim.x + threadIdx.x) >> 6;
    int lane = threadIdx.x & 63;
    if (w >= batch) return;
    int uu = user[w], ii = item_i[w], jj = item_j[w];

    size_t uo = (size_t)uu * FACTOR + lane;
    float g1 = bf2f(g1u[uo]);
    float U  = eu[uo] + g1 + g1 * d_i[uu] + gather_dot(cs_u, ptr_u[uu], ptr_u[uu + 1], g1i, lane);

    size_t io = (size_t)ii * FACTOR + lane;
    float h1 = bf2f(g1i[io]);
    float Pi = ei[io] + h1 + h1 * d_j[ii] + gather_dot(cs_i, ptr_i[ii], ptr_i[ii + 1], g1u, lane);

    size_t jo = (size_t)jj * FACTOR + lane;
    float h1j = bf2f(g1i[jo]);
    float Pj = ei[jo] + h1j + h1j * d_j[jj] + gather_dot(cs_i, ptr_i[jj], ptr_i[jj + 1], g1u, lane);

    float di  = U * Pi;
    float dj  = U * Pj;
    float su2 = U * U;
    float sp2 = Pi * Pi + Pj * Pj;
    for (int off = 32; off; off >>= 1) {
        di  += __shfl_down(di,  off, 64);
        dj  += __shfl_down(dj,  off, 64);
        su2 += __shfl_down(su2, off, 64);
        sp2 += __shfl_down(sp2, off, 64);
    }
    if (lane == 0) {
        float x  = -(di - dj);
        float sp = fmaxf(x, 0.f) + log1pf(expf(-fabsf(x)));
        atomicAdd(acc + 0, su2);
        atomicAdd(acc + 1, sp2);
        atomicAdd(acc + 2, sp);
    }
}

__global__ void finalize(const float* __restrict__ acc, float* __restrict__ out, int batch) {
    if (threadIdx.x == 0 && blockIdx.x == 0) {
        float inv_b  = 1.0f / (float)batch;
        float inv_bf = 1.0f / (float)(batch * FACTOR);
        out[0] = acc[2] * inv_b + LAMADA * acc[0] * inv_bf + LAMADA * acc[1] * inv_bf;
    }
}

// ---------------- fallback (atomic, fp32) path ----------------
__global__ void init_scale(const float* __restrict__ src, const float* __restrict__ d,
                           float* __restrict__ dst, int n_rows) {
    int gid = blockIdx.x * blockDim.x + threadIdx.x;
    int total = n_rows * 16;
    if (gid >= total) return;
    int r = gid >> 4;
    float s = d[r];
    float4 v = ((const float4*)src)[gid];
    v.x *= s; v.y *= s; v.z *= s; v.w *= s;
    ((float4*)dst)[gid] = v;
}

__global__ void edge_spmm(const float* __restrict__ srcU, const float* __restrict__ srcI,
                          float* __restrict__ dstU, float* __restrict__ dstI,
                          const int* __restrict__ u_idx, const int* __restrict__ i_idx,
                          const float* __restrict__ ui_vals, const float* __restrict__ iu_vals,
                          int n_edges) {
    long long gid = (long long)blockIdx.x * blockDim.x + threadIdx.x;
    int e = (int)(gid >> 4);
    if (e >= n_edges) return;
    int sub = ((int)gid & 15) * 4;
    int u = u_idx[e], i = i_idx[e];
    float uv = ui_vals[e], iv = iu_vals[e];
    size_t uo = (size_t)u * FACTOR + sub;
    size_t io = (size_t)i * FACTOR + sub;
    float4 a = *(const float4*)(srcI + io);
    float4 b = *(const float4*)(srcU + uo);
    float* du = dstU + uo;
    float* di = dstI + io;
    atomicAdd(du + 0, a.x * uv); atomicAdd(du + 1, a.y * uv);
    atomicAdd(du + 2, a.z * uv); atomicAdd(du + 3, a.w * uv);
    atomicAdd(di + 0, b.x * iv); atomicAdd(di + 1, b.y * iv);
    atomicAdd(di + 2, b.z * iv); atomicAdd(di + 3, b.w * iv);
}

__global__ void batch_loss(const float* __restrict__ eu, const float* __restrict__ ei,
                           const float* __restrict__ g1u, const float* __restrict__ g1i,
                           const float* __restrict__ g2u, const float* __restrict__ g2i,
                           const int* __restrict__ user, const int* __restrict__ item_i,
                           const int* __restrict__ item_j, float* __restrict__ acc, int batch) {
    int gid = blockIdx.x * blockDim.x + threadIdx.x;
    int w = gid >> 6;
    int lane = threadIdx.x & 63;
    if (w >= batch) return;
    int uu = user[w], ii = item_i[w], jj = item_j[w];
    size_t uo = (size_t)uu * FACTOR + lane;
    size_t io = (size_t)ii * FACTOR + lane;
    size_t jo = (size_t)jj * FACTOR + lane;
    float uvv = eu[uo] + g1u[uo] + g2u[uo];
    float piv = ei[io] + g1i[io] + g2i[io];
    float pjv = ei[jo] + g1i[jo] + g2i[jo];
    float di  = uvv * piv;
    float dj  = uvv * pjv;
    float su2 = uvv * uvv;
    float sp2 = piv * piv + pjv * pjv;
    for (int off = 32; off; off >>= 1) {
        di  += __shfl_down(di,  off, 64);
        dj  += __shfl_down(dj,  off, 64);
        su2 += __shfl_down(su2, off, 64);
        sp2 += __shfl_down(sp2, off, 64);
    }
    if (lane == 0) {
        float x  = -(di - dj);
        float sp = fmaxf(x, 0.f) + log1pf(expf(-fabsf(x)));
        atomicAdd(acc + 0, su2);
        atomicAdd(acc + 1, sp2);
        atomicAdd(acc + 2, sp);
    }
}

extern "C" void kernel_launch(void* const* d_in, const int* in_sizes, int n_in,
                              void* d_out, int out_size, void* d_ws, size_t ws_size,
                              hipStream_t stream) {
    const float* eu      = (const float*)d_in[0];
    const float* ei      = (const float*)d_in[1];
    const int*   u_idx   = (const int*)d_in[2];
    const int*   i_idx   = (const int*)d_in[3];
    const float* ui_vals = (const float*)d_in[4];
    const float* iu_vals = (const float*)d_in[5];
    const float* d_i     = (const float*)d_in[6];
    const float* d_j     = (const float*)d_in[7];
    const int*   user    = (const int*)d_in[8];
    const int*   item_i  = (const int*)d_in[9];
    const int*   item_j  = (const int*)d_in[10];
    int n_edges = in_sizes[2];
    int batch   = in_sizes[8];
    float* out  = (float*)d_out;

    const size_t FU = (size_t)USER_NUM * FACTOR;   // 6.4M elems
    const size_t FI = (size_t)ITEM_NUM * FACTOR;   // 3.2M elems
    const size_t NE = (size_t)n_edges;

    // Workspace layout (region A' = bf16 tables, 38.4MB; staged_i overlays it):
    //   A': g1u_b | g1i_b | beu | bei   (ushort, total (FU+FI)*2 elems)
    //   B : cs_u (NE int2)   C : cs_i (NE int2)
    //   staged_i = overlay A' (25.6MB <= 38.4MB), consumed by finalize_i
    //   staged_u = overlay C, consumed by finalize_u before cs_i written
    // Order: count -> scan -> place -> fin_u(C->B) -> fin_i(A'->C)
    //        -> to_bf16(inputs->A') -> spmm2(A',B,C -> A') -> fused_batch
    ushort_t* g1u_b = (ushort_t*)d_ws;              // FU
    ushort_t* g1i_b = g1u_b + FU;                   // FI
    ushort_t* beu   = g1i_b + FI;                   // FU
    ushort_t* bei   = beu + FU;                     // FI
    int2*  cs_u  = (int2*)(bei + FI);               // NE (8B aligned: (FU+FI)*2*2 bytes = 38.4MB)
    int2*  cs_i  = cs_u + NE;                       // NE
    int2*  staged_i = (int2*)d_ws;                  // overlay A'
    int2*  staged_u = cs_i;                         // overlay C
    int*   ptr_u = (int*)(cs_i + NE);               // USER_NUM+1
    int*   ptr_i = ptr_u + (USER_NUM + 1);          // ITEM_NUM+1
    int*   cnt_u = ptr_i + (ITEM_NUM + 1);          // NBU
    int*   cnt_i = cnt_u + NBU;                     // NBI
    int*   base_u = cnt_i + NBI;                    // NBU+1
    int*   base_i = base_u + (NBU + 1);             // NBI+1
    int*   cur_u  = base_i + (NBI + 1);             // NBU
    int*   cur_i  = cur_u + NBU;                    // NBI
    float* acc    = (float*)(cur_i + NBI);          // 4

    size_t need_bytes = ((size_t)(acc + 4) - (size_t)d_ws);

    if (ws_size >= need_bytes) {
        int nb1 = (n_edges + CHUNK - 1) / CHUNK;
        hipMemsetAsync(cnt_u, 0, (size_t)(NBU + NBI) * sizeof(int), stream);

        count_buckets<<<nb1, 256, 0, stream>>>(u_idx, i_idx, cnt_u, cnt_i, n_edges);
        bucket_scan<<<1, 512, 0, stream>>>(cnt_u, cnt_i, base_u, base_i, cur_u, cur_i,
                                           ptr_u + USER_NUM, ptr_i + ITEM_NUM, acc, n_edges);
        place<<<nb1, 256, 0, stream>>>(u_idx, i_idx, ui_vals, iu_vals,
                                       cur_u, cur_i, staged_u, staged_i, n_edges);
        bucket_finalize<<<NBU, 256, 0, stream>>>(staged_u, base_u, ptr_u, cs_u, USER_NUM);
        bucket_finalize<<<NBI, 256, 0, stream>>>(staged_i, base_i, ptr_i, cs_i, ITEM_NUM);

        // convert input tables to bf16 (staged_i dead now)
        to_bf16<<<(int)((FU / 4 + 255) / 256), 256, 0, stream>>>(eu, beu, (int)(FU / 4));
        to_bf16<<<(int)((FI / 4 + 255) / 256), 256, 0, stream>>>(ei, bei, (int)(FI / 4));

        int total_waves = USER_NUM + ITEM_NUM;
        csr_spmm2<<<(total_waves * 64 + 255) / 256, 256, 0, stream>>>(
            ptr_u, cs_u, ptr_i, cs_i, beu, bei, eu, ei, d_i, d_j, g1u_b, g1i_b);

        fused_batch<<<(batch * 64 + 255) / 256, 256, 0, stream>>>(eu, ei, g1u_b, g1i_b,
                                                                  ptr_u, cs_u, ptr_i, cs_i,
                                                                  d_i, d_j, user, item_i, item_j,
                                                                  acc, batch);
        finalize<<<1, 64, 0, stream>>>(acc, out, batch);
    } else {
        // fallback: fp32 atomic scatter path (77MB)
        float* f_g1u = (float*)d_ws;
        float* f_g1i = f_g1u + FU;
        float* f_g2u = f_g1i + FI;
        float* f_g2i = f_g2u + FU;
        float* f_acc = f_g2i + FI;
        hipMemsetAsync(f_acc, 0, 4 * sizeof(float), stream);
        long long tot = (long long)n_edges * 16;
        int eblocks = (int)((tot + 255) / 256);
        init_scale<<<(USER_NUM * 16 + 255) / 256, 256, 0, stream>>>(eu, d_i, f_g1u, USER_NUM);
        init_scale<<<(ITEM_NUM * 16 + 255) / 256, 256, 0, stream>>>(ei, d_j, f_g1i, ITEM_NUM);
        edge_spmm<<<eblocks, 256, 0, stream>>>(eu, ei, f_g1u, f_g1i, u_idx, i_idx, ui_vals, iu_vals, n_edges);
        init_scale<<<(USER_NUM * 16 + 255) / 256, 256, 0, stream>>>(f_g1u, d_i, f_g2u, USER_NUM);
        init_scale<<<(ITEM_NUM * 16 + 255) / 256, 256, 0, stream>>>(f_g1i, d_j, f_g2i, ITEM_NUM);
        edge_spmm<<<eblocks, 256, 0, stream>>>(f_g1u, f_g1i, f_g2u, f_g2i, u_idx, i_idx, ui_vals, iu_vals, n_edges);
        batch_loss<<<(batch * 64 + 255) / 256, 256, 0, stream>>>(eu, ei, f_g1u, f_g1i, f_g2u, f_g2i,
                                                                 user, item_i, item_j, f_acc, batch);
        finalize<<<1, 64, 0, stream>>>(f_acc, out, batch);
    }
}

// Round 9
// 709.467 us; speedup vs baseline: 15.5401x; 1.0368x over previous
//
#include <hip/hip_runtime.h>
#include <math.h>

#define USER_NUM 100000
#define ITEM_NUM 50000
#define FACTOR   64
#define LAMADA   0.0001f

#define NBU   391     // ceil(100000/256) buckets of 256 user rows
#define NBI   196     // ceil(50000/256)  buckets of 256 item rows
#define CHUNK 8192    // edges per partition block

typedef unsigned short ushort_t;
typedef unsigned int   uint_t;

__device__ __forceinline__ ushort_t f2bf(float f) {
    uint_t u = __float_as_uint(f);
    u += 0x7FFFu + ((u >> 16) & 1u);        // round-to-nearest-even
    return (ushort_t)(u >> 16);
}
__device__ __forceinline__ float bf2f(ushort_t h) {
    return __uint_as_float((uint_t)h << 16);
}
__device__ __forceinline__ float bflo(uint_t u) { return __uint_as_float(u << 16); }
__device__ __forceinline__ float bfhi(uint_t u) { return __uint_as_float(u & 0xFFFF0000u); }

// ---------------- fp32 -> bf16 table convert (4 floats/thread) --------------
__global__ void to_bf16(const float* __restrict__ src, ushort_t* __restrict__ dst, int n4) {
    int gid = blockIdx.x * blockDim.x + threadIdx.x;
    if (gid >= n4) return;
    float4 v = ((const float4*)src)[gid];
    ushort4 o;
    o.x = f2bf(v.x); o.y = f2bf(v.y); o.z = f2bf(v.z); o.w = f2bf(v.w);
    ((ushort4*)dst)[gid] = o;
}

// ---------------- build: per-block bucket count -> global counters ----------
__global__ void count_buckets(const int* __restrict__ u_idx, const int* __restrict__ i_idx,
                              int* __restrict__ cnt_u, int* __restrict__ cnt_i, int n_edges) {
    __shared__ int s_u[NBU];
    __shared__ int s_i[NBI];
    int tid = threadIdx.x;
    for (int b = tid; b < NBU; b += 256) s_u[b] = 0;
    for (int b = tid; b < NBI; b += 256) s_i[b] = 0;
    __syncthreads();
    int start = blockIdx.x * CHUNK, end = min(start + CHUNK, n_edges);
    for (int e = start + tid; e < end; e += 256) {
        atomicAdd(&s_u[u_idx[e] >> 8], 1);
        atomicAdd(&s_i[i_idx[e] >> 8], 1);
    }
    __syncthreads();
    for (int b = tid; b < NBU; b += 256) { int c = s_u[b]; if (c) atomicAdd(&cnt_u[b], c); }
    for (int b = tid; b < NBI; b += 256) { int c = s_i[b]; if (c) atomicAdd(&cnt_i[b], c); }
}

// ---------------- build: scan bucket totals -> exact bases + cursors --------
__global__ void bucket_scan(const int* __restrict__ cnt_u, const int* __restrict__ cnt_i,
                            int* __restrict__ base_u, int* __restrict__ base_i,
                            int* __restrict__ cur_u, int* __restrict__ cur_i,
                            int* __restrict__ ptr_u_end, int* __restrict__ ptr_i_end,
                            float* __restrict__ acc, int n_edges) {
    __shared__ int s[512];
    int tid = threadIdx.x;
    if (tid < 4) acc[tid] = 0.f;
    int x = (tid < NBU) ? cnt_u[tid] : 0;
    s[tid] = x; __syncthreads();
    for (int off = 1; off < 512; off <<= 1) {
        int t = (tid >= off) ? s[tid - off] : 0;
        __syncthreads(); s[tid] += t; __syncthreads();
    }
    if (tid < NBU) { int b = s[tid] - x; base_u[tid] = b; cur_u[tid] = b; }
    if (tid == 511) { base_u[NBU] = s[511]; *ptr_u_end = n_edges; }
    __syncthreads();
    int y = (tid < NBI) ? cnt_i[tid] : 0;
    s[tid] = y; __syncthreads();
    for (int off = 1; off < 512; off <<= 1) {
        int t = (tid >= off) ? s[tid - off] : 0;
        __syncthreads(); s[tid] += t; __syncthreads();
    }
    if (tid < NBI) { int b = s[tid] - y; base_i[tid] = b; cur_i[tid] = b; }
    if (tid == 511) { base_i[NBI] = s[511]; *ptr_i_end = n_edges; }
}

// ---------------- build: place packed (rowlocal<<20|col, val) into staging --
__global__ void place(const int* __restrict__ u_idx, const int* __restrict__ i_idx,
                      const float* __restrict__ ui_vals, const float* __restrict__ iu_vals,
                      int* __restrict__ cur_u, int* __restrict__ cur_i,
                      int2* __restrict__ staged_u, int2* __restrict__ staged_i, int n_edges) {
    __shared__ int s_u[NBU];
    __shared__ int s_i[NBI];
    int tid = threadIdx.x;
    for (int b = tid; b < NBU; b += 256) s_u[b] = 0;
    for (int b = tid; b < NBI; b += 256) s_i[b] = 0;
    __syncthreads();
    int start = blockIdx.x * CHUNK, end = min(start + CHUNK, n_edges);
    for (int e = start + tid; e < end; e += 256) {
        atomicAdd(&s_u[u_idx[e] >> 8], 1);
        atomicAdd(&s_i[i_idx[e] >> 8], 1);
    }
    __syncthreads();
    for (int b = tid; b < NBU; b += 256) { int c = s_u[b]; s_u[b] = c ? atomicAdd(&cur_u[b], c) : 0; }
    for (int b = tid; b < NBI; b += 256) { int c = s_i[b]; s_i[b] = c ? atomicAdd(&cur_i[b], c) : 0; }
    __syncthreads();
    for (int e = start + tid; e < end; e += 256) {
        int u = u_idx[e], i = i_idx[e];
        int pu = atomicAdd(&s_u[u >> 8], 1);
        staged_u[pu] = make_int2(((u & 255) << 20) | i, __float_as_int(ui_vals[e]));
        int pi = atomicAdd(&s_i[i >> 8], 1);
        staged_i[pi] = make_int2(((i & 255) << 20) | u, __float_as_int(iu_vals[e]));
    }
}

// ---------------- build: per-bucket finalize (ptr + CSR), streams staging ---
__global__ void bucket_finalize(const int2* __restrict__ staged, const int* __restrict__ base,
                                int* __restrict__ ptr, int2* __restrict__ cs, int n_rows) {
    __shared__ int s_cnt[256];
    __shared__ int s_pos[256];
    int b = blockIdx.x, tid = threadIdx.x;
    int sbase = base[b], nE = base[b + 1] - sbase;
    s_cnt[tid] = 0;
    __syncthreads();
    for (int k = tid; k < nE; k += 256) atomicAdd(&s_cnt[staged[sbase + k].x >> 20], 1);
    __syncthreads();
    int x = s_cnt[tid];
    s_pos[tid] = x; __syncthreads();
    for (int off = 1; off < 256; off <<= 1) {
        int t = (tid >= off) ? s_pos[tid - off] : 0;
        __syncthreads(); s_pos[tid] += t; __syncthreads();
    }
    int excl = s_pos[tid] - x + sbase;
    int r = (b << 8) + tid;
    if (r < n_rows) ptr[r] = excl;
    s_pos[tid] = excl;
    __syncthreads();
    for (int k = tid; k < nE; k += 256) {
        int2 se = staged[sbase + k];
        int rl = se.x >> 20;
        int pos = atomicAdd(&s_pos[rl], 1);
        cs[pos] = make_int2(se.x & 0xFFFFF, se.y);
    }
}

// -------- packed gather-dot: 2 edges/iter (half=lane>>5), 2 feats/lane ------
// Returns the cross-half-combined float2 (valid & identical in all lanes).
__device__ __forceinline__ float2 gather_dot2(const int2* __restrict__ cs, int start, int end,
                                              const uint_t* __restrict__ tab32, int fp, int half) {
    float ax = 0.f, ay = 0.f, bx = 0.f, by = 0.f;
    int k = start;
    for (; k + 8 <= end; k += 8) {
        int2 c0 = cs[k + 0 + half];
        int2 c1 = cs[k + 2 + half];
        int2 c2 = cs[k + 4 + half];
        int2 c3 = cs[k + 6 + half];
        uint_t u0 = tab32[c0.x * 32 + fp];
        uint_t u1 = tab32[c1.x * 32 + fp];
        uint_t u2 = tab32[c2.x * 32 + fp];
        uint_t u3 = tab32[c3.x * 32 + fp];
        float v0 = __int_as_float(c0.y), v1 = __int_as_float(c1.y);
        float v2 = __int_as_float(c2.y), v3 = __int_as_float(c3.y);
        ax = fmaf(v0, bflo(u0), ax); ay = fmaf(v0, bfhi(u0), ay);
        bx = fmaf(v1, bflo(u1), bx); by = fmaf(v1, bfhi(u1), by);
        ax = fmaf(v2, bflo(u2), ax); ay = fmaf(v2, bfhi(u2), ay);
        bx = fmaf(v3, bflo(u3), bx); by = fmaf(v3, bfhi(u3), by);
    }
    for (; k + 2 <= end; k += 2) {
        int2 c0 = cs[k + half];
        uint_t u0 = tab32[c0.x * 32 + fp];
        float v0 = __int_as_float(c0.y);
        ax = fmaf(v0, bflo(u0), ax); ay = fmaf(v0, bfhi(u0), ay);
    }
    if (k < end && half == 0) {
        int2 c0 = cs[k];
        uint_t u0 = tab32[c0.x * 32 + fp];
        float v0 = __int_as_float(c0.y);
        ax = fmaf(v0, bflo(u0), ax); ay = fmaf(v0, bfhi(u0), ay);
    }
    float2 r; r.x = ax + bx; r.y = ay + by;
    r.x += __shfl_xor(r.x, 32, 64);
    r.y += __shfl_xor(r.y, 32, 64);
    return r;
}

// ---------------- merged layer-1 SPMM, packed bf16 pairs --------------------
__global__ void csr_spmm3(const int* __restrict__ ptr_u, const int2* __restrict__ cs_u,
                          const int* __restrict__ ptr_i, const int2* __restrict__ cs_i,
                          const uint_t* __restrict__ beu32, const uint_t* __restrict__ bei32,
                          const float* __restrict__ eu, const float* __restrict__ ei,
                          const float* __restrict__ d_i, const float* __restrict__ d_j,
                          uint_t* __restrict__ g1u32, uint_t* __restrict__ g1i32) {
    int w = (blockIdx.x * blockDim.x + threadIdx.x) >> 6;
    int lane = threadIdx.x & 63;
    int half = lane >> 5, fp = lane & 31;
    const int* ptr; const int2* cs; const uint_t* src; const float* self;
    const float* d; uint_t* out; int row;
    if (w < USER_NUM) {
        row = w; ptr = ptr_u; cs = cs_u; src = bei32; self = eu; d = d_i; out = g1u32;
    } else if (w < USER_NUM + ITEM_NUM) {
        row = w - USER_NUM; ptr = ptr_i; cs = cs_i; src = beu32; self = ei; d = d_j; out = g1i32;
    } else return;
    int start = ptr[row], end = ptr[row + 1];
    float2 g = gather_dot2(cs, start, end, src, fp, half);
    if (half == 0) {
        float2 sv = ((const float2*)self)[row * 32 + fp];
        float dv = d[row];
        float ox = g.x + sv.x * dv;
        float oy = g.y + sv.y * dv;
        out[row * 32 + fp] = (uint_t)f2bf(ox) | ((uint_t)f2bf(oy) << 16);
    }
}

// ---------------- fused layer-2 + loss (packed) ----------------
__global__ void fused_batch(const float* __restrict__ eu, const float* __restrict__ ei,
                            const uint_t* __restrict__ g1u32, const uint_t* __restrict__ g1i32,
                            const int* __restrict__ ptr_u, const int2* __restrict__ cs_u,
                            const int* __restrict__ ptr_i, const int2* __restrict__ cs_i,
                            const float* __restrict__ d_i, const float* __restrict__ d_j,
                            const int* __restrict__ user, const int* __restrict__ item_i,
                            const int* __restrict__ item_j, float* __restrict__ acc, int batch) {
    int w = (blockIdx.x * blockDim.x + threadIdx.x) >> 6;
    int lane = threadIdx.x & 63;
    int half = lane >> 5, fp = lane & 31;
    if (w >= batch) return;
    int uu = user[w], ii = item_i[w], jj = item_j[w];

    float2 gu = gather_dot2(cs_u, ptr_u[uu], ptr_u[uu + 1], g1i32, fp, half);
    uint_t g1 = g1u32[uu * 32 + fp];
    float2 e2 = ((const float2*)eu)[uu * 32 + fp];
    float scu = 1.f + d_i[uu];
    float Ux = e2.x + bflo(g1) * scu + gu.x;
    float Uy = e2.y + bfhi(g1) * scu + gu.y;

    float2 gi = gather_dot2(cs_i, ptr_i[ii], ptr_i[ii + 1], g1u32, fp, half);
    uint_t h1 = g1i32[ii * 32 + fp];
    float2 f2 = ((const float2*)ei)[ii * 32 + fp];
    float sci = 1.f + d_j[ii];
    float Pix = f2.x + bflo(h1) * sci + gi.x;
    float Piy = f2.y + bfhi(h1) * sci + gi.y;

    float2 gj = gather_dot2(cs_i, ptr_i[jj], ptr_i[jj + 1], g1u32, fp, half);
    uint_t h1j = g1i32[jj * 32 + fp];
    float2 f2j = ((const float2*)ei)[jj * 32 + fp];
    float scj = 1.f + d_j[jj];
    float Pjx = f2j.x + bflo(h1j) * scj + gj.x;
    float Pjy = f2j.y + bfhi(h1j) * scj + gj.y;

    // values are duplicated across halves -> reduce over 64 lanes, scale by 0.5
    float di  = Ux * Pix + Uy * Piy;
    float dj  = Ux * Pjx + Uy * Pjy;
    float su2 = Ux * Ux + Uy * Uy;
    float sp2 = Pix * Pix + Piy * Piy + Pjx * Pjx + Pjy * Pjy;
    for (int off = 32; off; off >>= 1) {
        di  += __shfl_down(di,  off, 64);
        dj  += __shfl_down(dj,  off, 64);
        su2 += __shfl_down(su2, off, 64);
        sp2 += __shfl_down(sp2, off, 64);
    }
    if (lane == 0) {
        di *= 0.5f; dj *= 0.5f; su2 *= 0.5f; sp2 *= 0.5f;
        float x  = -(di - dj);
        float sp = fmaxf(x, 0.f) + log1pf(expf(-fabsf(x)));
        atomicAdd(acc + 0, su2);
        atomicAdd(acc + 1, sp2);
        atomicAdd(acc + 2, sp);
    }
}

__global__ void finalize(const float* __restrict__ acc, float* __restrict__ out, int batch) {
    if (threadIdx.x == 0 && blockIdx.x == 0) {
        float inv_b  = 1.0f / (float)batch;
        float inv_bf = 1.0f / (float)(batch * FACTOR);
        out[0] = acc[2] * inv_b + LAMADA * acc[0] * inv_bf + LAMADA * acc[1] * inv_bf;
    }
}

// ---------------- fallback (atomic, fp32) path ----------------
__global__ void init_scale(const float* __restrict__ src, const float* __restrict__ d,
                           float* __restrict__ dst, int n_rows) {
    int gid = blockIdx.x * blockDim.x + threadIdx.x;
    int total = n_rows * 16;
    if (gid >= total) return;
    int r = gid >> 4;
    float s = d[r];
    float4 v = ((const float4*)src)[gid];
    v.x *= s; v.y *= s; v.z *= s; v.w *= s;
    ((float4*)dst)[gid] = v;
}

__global__ void edge_spmm(const float* __restrict__ srcU, const float* __restrict__ srcI,
                          float* __restrict__ dstU, float* __restrict__ dstI,
                          const int* __restrict__ u_idx, const int* __restrict__ i_idx,
                          const float* __restrict__ ui_vals, const float* __restrict__ iu_vals,
                          int n_edges) {
    long long gid = (long long)blockIdx.x * blockDim.x + threadIdx.x;
    int e = (int)(gid >> 4);
    if (e >= n_edges) return;
    int sub = ((int)gid & 15) * 4;
    int u = u_idx[e], i = i_idx[e];
    float uv = ui_vals[e], iv = iu_vals[e];
    size_t uo = (size_t)u * FACTOR + sub;
    size_t io = (size_t)i * FACTOR + sub;
    float4 a = *(const float4*)(srcI + io);
    float4 b = *(const float4*)(srcU + uo);
    float* du = dstU + uo;
    float* di = dstI + io;
    atomicAdd(du + 0, a.x * uv); atomicAdd(du + 1, a.y * uv);
    atomicAdd(du + 2, a.z * uv); atomicAdd(du + 3, a.w * uv);
    atomicAdd(di + 0, b.x * iv); atomicAdd(di + 1, b.y * iv);
    atomicAdd(di + 2, b.z * iv); atomicAdd(di + 3, b.w * iv);
}

__global__ void batch_loss(const float* __restrict__ eu, const float* __restrict__ ei,
                           const float* __restrict__ g1u, const float* __restrict__ g1i,
                           const float* __restrict__ g2u, const float* __restrict__ g2i,
                           const int* __restrict__ user, const int* __restrict__ item_i,
                           const int* __restrict__ item_j, float* __restrict__ acc, int batch) {
    int gid = blockIdx.x * blockDim.x + threadIdx.x;
    int w = gid >> 6;
    int lane = threadIdx.x & 63;
    if (w >= batch) return;
    int uu = user[w], ii = item_i[w], jj = item_j[w];
    size_t uo = (size_t)uu * FACTOR + lane;
    size_t io = (size_t)ii * FACTOR + lane;
    size_t jo = (size_t)jj * FACTOR + lane;
    float uvv = eu[uo] + g1u[uo] + g2u[uo];
    float piv = ei[io] + g1i[io] + g2i[io];
    float pjv = ei[jo] + g1i[jo] + g2i[jo];
    float di  = uvv * piv;
    float dj  = uvv * pjv;
    float su2 = uvv * uvv;
    float sp2 = piv * piv + pjv * pjv;
    for (int off = 32; off; off >>= 1) {
        di  += __shfl_down(di,  off, 64);
        dj  += __shfl_down(dj,  off, 64);
        su2 += __shfl_down(su2, off, 64);
        sp2 += __shfl_down(sp2, off, 64);
    }
    if (lane == 0) {
        float x  = -(di - dj);
        float sp = fmaxf(x, 0.f) + log1pf(expf(-fabsf(x)));
        atomicAdd(acc + 0, su2);
        atomicAdd(acc + 1, sp2);
        atomicAdd(acc + 2, sp);
    }
}

extern "C" void kernel_launch(void* const* d_in, const int* in_sizes, int n_in,
                              void* d_out, int out_size, void* d_ws, size_t ws_size,
                              hipStream_t stream) {
    const float* eu      = (const float*)d_in[0];
    const float* ei      = (const float*)d_in[1];
    const int*   u_idx   = (const int*)d_in[2];
    const int*   i_idx   = (const int*)d_in[3];
    const float* ui_vals = (const float*)d_in[4];
    const float* iu_vals = (const float*)d_in[5];
    const float* d_i     = (const float*)d_in[6];
    const float* d_j     = (const float*)d_in[7];
    const int*   user    = (const int*)d_in[8];
    const int*   item_i  = (const int*)d_in[9];
    const int*   item_j  = (const int*)d_in[10];
    int n_edges = in_sizes[2];
    int batch   = in_sizes[8];
    float* out  = (float*)d_out;

    const size_t FU = (size_t)USER_NUM * FACTOR;   // 6.4M elems
    const size_t FI = (size_t)ITEM_NUM * FACTOR;   // 3.2M elems
    const size_t NE = (size_t)n_edges;

    // Workspace layout (A' = bf16 tables 38.4MB; staged_i overlays it):
    //   A': g1u_b | g1i_b | beu | bei   B: cs_u   C: cs_i
    // Order: count -> scan -> place -> fin_u(C->B) -> fin_i(A'->C)
    //        -> to_bf16(inputs->A') -> spmm3 -> fused_batch
    ushort_t* g1u_b = (ushort_t*)d_ws;              // FU
    ushort_t* g1i_b = g1u_b + FU;                   // FI
    ushort_t* beu   = g1i_b + FI;                   // FU
    ushort_t* bei   = beu + FU;                     // FI
    int2*  cs_u  = (int2*)(bei + FI);               // NE
    int2*  cs_i  = cs_u + NE;                       // NE
    int2*  staged_i = (int2*)d_ws;                  // overlay A'
    int2*  staged_u = cs_i;                         // overlay C
    int*   ptr_u = (int*)(cs_i + NE);               // USER_NUM+1
    int*   ptr_i = ptr_u + (USER_NUM + 1);          // ITEM_NUM+1
    int*   cnt_u = ptr_i + (ITEM_NUM + 1);          // NBU
    int*   cnt_i = cnt_u + NBU;                     // NBI
    int*   base_u = cnt_i + NBI;                    // NBU+1
    int*   base_i = base_u + (NBU + 1);             // NBI+1
    int*   cur_u  = base_i + (NBI + 1);             // NBU
    int*   cur_i  = cur_u + NBU;                    // NBI
    float* acc    = (float*)(cur_i + NBI);          // 4

    size_t need_bytes = ((size_t)(acc + 4) - (size_t)d_ws);

    if (ws_size >= need_bytes) {
        int nb1 = (n_edges + CHUNK - 1) / CHUNK;
        hipMemsetAsync(cnt_u, 0, (size_t)(NBU + NBI) * sizeof(int), stream);

        count_buckets<<<nb1, 256, 0, stream>>>(u_idx, i_idx, cnt_u, cnt_i, n_edges);
        bucket_scan<<<1, 512, 0, stream>>>(cnt_u, cnt_i, base_u, base_i, cur_u, cur_i,
                                           ptr_u + USER_NUM, ptr_i + ITEM_NUM, acc, n_edges);
        place<<<nb1, 256, 0, stream>>>(u_idx, i_idx, ui_vals, iu_vals,
                                       cur_u, cur_i, staged_u, staged_i, n_edges);
        bucket_finalize<<<NBU, 256, 0, stream>>>(staged_u, base_u, ptr_u, cs_u, USER_NUM);
        bucket_finalize<<<NBI, 256, 0, stream>>>(staged_i, base_i, ptr_i, cs_i, ITEM_NUM);

        // convert input tables to bf16 (staged_i dead now)
        to_bf16<<<(int)((FU / 4 + 255) / 256), 256, 0, stream>>>(eu, beu, (int)(FU / 4));
        to_bf16<<<(int)((FI / 4 + 255) / 256), 256, 0, stream>>>(ei, bei, (int)(FI / 4));

        int total_waves = USER_NUM + ITEM_NUM;
        csr_spmm3<<<(total_waves * 64 + 255) / 256, 256, 0, stream>>>(
            ptr_u, cs_u, ptr_i, cs_i, (const uint_t*)beu, (const uint_t*)bei,
            eu, ei, d_i, d_j, (uint_t*)g1u_b, (uint_t*)g1i_b);

        fused_batch<<<(batch * 64 + 255) / 256, 256, 0, stream>>>(
            eu, ei, (const uint_t*)g1u_b, (const uint_t*)g1i_b,
            ptr_u, cs_u, ptr_i, cs_i, d_i, d_j, user, item_i, item_j, acc, batch);
        finalize<<<1, 64, 0, stream>>>(acc, out, batch);
    } else {
        // fallback: fp32 atomic scatter path (77MB)
        float* f_g1u = (float*)d_ws;
        float* f_g1i = f_g1u + FU;
        float* f_g2u = f_g1i + FI;
        float* f_g2i = f_g2u + FU;
        float* f_acc = f_g2i + FI;
        hipMemsetAsync(f_acc, 0, 4 * sizeof(float), stream);
        long long tot = (long long)n_edges * 16;
        int eblocks = (int)((tot + 255) / 256);
        init_scale<<<(USER_NUM * 16 + 255) / 256, 256, 0, stream>>>(eu, d_i, f_g1u, USER_NUM);
        init_scale<<<(ITEM_NUM * 16 + 255) / 256, 256, 0, stream>>>(ei, d_j, f_g1i, ITEM_NUM);
        edge_spmm<<<eblocks, 256, 0, stream>>>(eu, ei, f_g1u, f_g1i, u_idx, i_idx, ui_vals, iu_vals, n_edges);
        init_scale<<<(USER_NUM * 16 + 255) / 256, 256, 0, stream>>>(f_g1u, d_i, f_g2u, USER_NUM);
        init_scale<<<(ITEM_NUM * 16 + 255) / 256, 256, 0, stream>>>(f_g1i, d_j, f_g2i, ITEM_NUM);
        edge_spmm<<<eblocks, 256, 0, stream>>>(f_g1u, f_g1i, f_g2u, f_g2i, u_idx, i_idx, ui_vals, iu_vals, n_edges);
        batch_loss<<<(batch * 64 + 255) / 256, 256, 0, stream>>>(eu, ei, f_g1u, f_g1i, f_g2u, f_g2i,
                                                                 user, item_i, item_j, f_acc, batch);
        finalize<<<1, 64, 0, stream>>>(f_acc, out, batch);
    }
}